// Round 1
// 295.826 us; speedup vs baseline: 1.0417x; 1.0417x over previous
//
#include <hip/hip_runtime.h>
#include <math.h>

// Problem constants (B=2, S=2048, D=1024, H=16, hd=64, K=16)
#define SEQ 2048
#define DIM 1024
#define NB  2
#define NH  16

typedef __attribute__((ext_vector_type(8))) short short8;
typedef __attribute__((ext_vector_type(4))) float floatx4;
typedef __attribute__((ext_vector_type(16))) float floatx16;

__device__ __forceinline__ ushort f2bf(float f) {
    unsigned u = __float_as_uint(f);
    return (ushort)((u + 0x7FFFu + ((u >> 16) & 1u)) >> 16);
}
__device__ __forceinline__ float bf2f(ushort h) {
    return __uint_as_float(((unsigned)h) << 16);
}
// async global->LDS, 16B per lane; LDS dest = wave-uniform base + lane*16
__device__ __forceinline__ void gload16(const void* g, char* lds_base) {
    __builtin_amdgcn_global_load_lds(
        (const __attribute__((address_space(1))) void*)g,
        (__attribute__((address_space(3))) void*)lds_base, 16, 0, 0);
}

// ---------------------------------------------------------------------------
// fp32 -> bf16 (hi only)
// ---------------------------------------------------------------------------
__global__ __launch_bounds__(256) void cvt_hi_kernel(
    const float* __restrict__ src, ushort* __restrict__ dst, int n)
{
    int i = (blockIdx.x * 256 + threadIdx.x) * 4;
    if (i >= n) return;
    float4 v = *(const float4*)(src + i);
    ushort4 o;
    o.x = f2bf(v.x); o.y = f2bf(v.y); o.z = f2bf(v.z); o.w = f2bf(v.w);
    *(ushort4*)(dst + i) = o;
}

// fp32 -> bf16 hi + lo (x ~= hi + lo, residual ~2^-17 relative)
__global__ __launch_bounds__(256) void cvt_split_kernel(
    const float* __restrict__ src, ushort* __restrict__ hi, ushort* __restrict__ lo, int n)
{
    int i = (blockIdx.x * 256 + threadIdx.x) * 4;
    if (i >= n) return;
    float4 v = *(const float4*)(src + i);
    ushort4 h, l;
    h.x = f2bf(v.x); l.x = f2bf(v.x - bf2f(h.x));
    h.y = f2bf(v.y); l.y = f2bf(v.y - bf2f(h.y));
    h.z = f2bf(v.z); l.z = f2bf(v.z - bf2f(h.z));
    h.w = f2bf(v.w); l.w = f2bf(v.w - bf2f(h.w));
    *(ushort4*)(hi + i) = h;
    *(ushort4*)(lo + i) = l;
}

// ---------------------------------------------------------------------------
// K1: per-diff stats
// ---------------------------------------------------------------------------
__global__ __launch_bounds__(256) void traj_stats_kernel(
    const float* __restrict__ x, float* __restrict__ sbuf, float* __restrict__ invbuf)
{
    const int wave = threadIdx.x >> 6;
    const int lane = threadIdx.x & 63;
    const int row  = blockIdx.x * 4 + wave;
    const int NR = NB * (SEQ - 1);
    if (row >= NR) return;
    const int b = row / (SEQ - 1);
    const int j = row - b * (SEQ - 1);
    const float* x0 = x + ((size_t)(b * SEQ + j)) * DIM;
    const float* x1 = x0 + DIM;
    float sum = 0.f;
    #pragma unroll
    for (int q = 0; q < 4; ++q) {
        int idx = q * 256 + lane * 4;
        float4 a = *(const float4*)(x0 + idx);
        float4 c = *(const float4*)(x1 + idx);
        float dx = c.x-a.x, dy = c.y-a.y, dz = c.z-a.z, dw = c.w-a.w;
        sum += dx*dx + dy*dy + dz*dz + dw*dw;
    }
    #pragma unroll
    for (int off = 32; off > 0; off >>= 1) sum += __shfl_down(sum, off);
    if (lane == 0) {
        float mag = sqrtf(sum);
        sbuf[row]   = tanhf(mag);
        invbuf[row] = 1.0f / fmaxf(mag, 1e-8f);
    }
}

// ---------------------------------------------------------------------------
// K2: traj combine (window <= 8)
// ---------------------------------------------------------------------------
__global__ __launch_bounds__(256) void traj_kernel(
    const float* __restrict__ x, const float* __restrict__ sbuf,
    const float* __restrict__ invbuf, float* __restrict__ traj_out)
{
    const int bp = blockIdx.x;
    const int b  = bp >> 11;
    const int p  = bp & (SEQ - 1);
    int ws = p - 8; if (ws < 0) ws = 0;
    const int wlen = p - ws;
    const float wsz = (float)((p - ws) > 1 ? (p - ws) : 1);
    const int base = b * (SEQ - 1) + ws;

    float Z = 0.f;
    for (int t = 0; t < wlen; ++t)
        Z += sbuf[base + t] * ((float)(t + 1) / wsz);
    const float scale = 1.0f / fmaxf(Z, 1e-8f);

    const int d0 = threadIdx.x * 4;
    const float* xb = x + ((size_t)(b * SEQ + ws)) * DIM + d0;
    float4 prev = *(const float4*)xb;
    float4 acc = make_float4(0.f,0.f,0.f,0.f);
    for (int t = 0; t < wlen; ++t) {
        xb += DIM;
        float4 cur = *(const float4*)xb;
        float cc = sbuf[base + t] * ((float)(t + 1) / wsz) * invbuf[base + t] * scale;
        acc.x += cc * (cur.x - prev.x);
        acc.y += cc * (cur.y - prev.y);
        acc.z += cc * (cur.z - prev.z);
        acc.w += cc * (cur.w - prev.w);
        prev = cur;
    }
    *(float4*)(traj_out + (size_t)bp * DIM + d0) = acc;
}

// ---------------------------------------------------------------------------
// MFMA bf16 GEMM, m97 structure: C[M,N] = A[M,1024] @ B[N,1024]^T.
// 128x128 tile, BK=32, 4 waves 2x2, each wave 64x64 via 4x4 of 16x16x32.
// SPLIT=1: A ~= Ah+Al, B ~= Bh+Bl; C = Ah·Bh + Ah·Bl + Al·Bh (fp32-ish).
// EPI=0: fp32 store to cout (ldc).
// EPI=2 (v^T): bf16 store to qwb[b][m][token&2047]  (vbt layout [B,1024,S]).
// EPI=3 (q/k): bf16 head-major store: n<1024 -> qwb, else kwb,
//              layout [(b*NH+h)*SEQ + s]*64 + d.
// ---------------------------------------------------------------------------
template<int SPLIT, int EPI>
__global__ __launch_bounds__(256) void mfma_gemm(
    const ushort* __restrict__ Ah, const ushort* __restrict__ Al,
    const ushort* __restrict__ Bh, const ushort* __restrict__ Bl,
    float* __restrict__ cout, int ldc,
    ushort* __restrict__ qwb, ushort* __restrict__ kwb)
{
    constexpr int SMEM = SPLIT ? 32768 : 16384;
    __shared__ char smem[SMEM];
    const int tid = threadIdx.x;
    const int l = tid & 63;
    const int w = tid >> 6;
    const int wm = w >> 1, wn = w & 1;
    const int n0 = blockIdx.x * 128;
    const int m0 = blockIdx.y * 128;

    char* a_h = smem;
    char* b_h = smem + 8192;
    char* a_l = smem + 16384;
    char* b_l = smem + 24576;

    const int srow = 32 * w + (l >> 2);
    const int scol = (l & 3) * 8;
    const ushort* Ahg = Ah + (size_t)(m0 + srow) * 1024 + scol;
    const ushort* Bhg = Bh + (size_t)(n0 + srow) * 1024 + scol;
    const ushort* Alg = SPLIT ? Al + (size_t)(m0 + srow) * 1024 + scol : nullptr;
    const ushort* Blg = SPLIT ? Bl + (size_t)(n0 + srow) * 1024 + scol : nullptr;

    floatx4 acc[4][4] = {};
    const int fr = l & 15;
    const int fq = (l >> 4) * 16;

    for (int kb = 0; kb < 1024; kb += 32) {
        if (kb) __syncthreads();
        gload16(Ahg + kb,             a_h + w*2048);
        gload16(Ahg + kb + 16*1024,   a_h + w*2048 + 1024);
        gload16(Bhg + kb,             b_h + w*2048);
        gload16(Bhg + kb + 16*1024,   b_h + w*2048 + 1024);
        if (SPLIT) {
            gload16(Alg + kb,           a_l + w*2048);
            gload16(Alg + kb + 16*1024, a_l + w*2048 + 1024);
            gload16(Blg + kb,           b_l + w*2048);
            gload16(Blg + kb + 16*1024, b_l + w*2048 + 1024);
        }
        __syncthreads();
        short8 fah[4], fbh[4], fal[4], fbl[4];
        #pragma unroll
        for (int t = 0; t < 4; ++t) {
            fah[t] = *(const short8*)(a_h + ((wm*64 + t*16 + fr) << 6) + fq);
            fbh[t] = *(const short8*)(b_h + ((wn*64 + t*16 + fr) << 6) + fq);
            if (SPLIT) {
                fal[t] = *(const short8*)(a_l + ((wm*64 + t*16 + fr) << 6) + fq);
                fbl[t] = *(const short8*)(b_l + ((wn*64 + t*16 + fr) << 6) + fq);
            }
        }
        #pragma unroll
        for (int it = 0; it < 4; ++it)
            #pragma unroll
            for (int jt = 0; jt < 4; ++jt) {
                acc[it][jt] = __builtin_amdgcn_mfma_f32_16x16x32_bf16(
                    fah[it], fbh[jt], acc[it][jt], 0, 0, 0);
                if (SPLIT) {
                    acc[it][jt] = __builtin_amdgcn_mfma_f32_16x16x32_bf16(
                        fah[it], fbl[jt], acc[it][jt], 0, 0, 0);
                    acc[it][jt] = __builtin_amdgcn_mfma_f32_16x16x32_bf16(
                        fal[it], fbh[jt], acc[it][jt], 0, 0, 0);
                }
            }
    }

    const int row0 = (l >> 4) * 4;   // C: row=(l>>4)*4+reg, col=l&15
    const int col  = l & 15;

    if (EPI == 0) {
        #pragma unroll
        for (int it = 0; it < 4; ++it)
            #pragma unroll
            for (int jt = 0; jt < 4; ++jt)
                #pragma unroll
                for (int r = 0; r < 4; ++r) {
                    int gm = m0 + wm*64 + it*16 + row0 + r;
                    int gn = n0 + wn*64 + jt*16 + col;
                    cout[(size_t)gm * ldc + gn] = acc[it][jt][r];
                }
    } else if (EPI == 2) {
        // transposed v store: rows m = h*64+d, cols n = token
        #pragma unroll
        for (int it = 0; it < 4; ++it)
            #pragma unroll
            for (int jt = 0; jt < 4; ++jt)
                #pragma unroll
                for (int r = 0; r < 4; ++r) {
                    int md = m0 + wm*64 + it*16 + row0 + r;
                    int t  = n0 + wn*64 + jt*16 + col;
                    int bb = t >> 11, ss = t & (SEQ - 1);
                    qwb[((size_t)bb << 21) + (size_t)md * SEQ + ss] = f2bf(acc[it][jt][r]);
                }
    } else {
        // q/k bf16 head-major store
        ushort* obuf = (n0 < 1024) ? qwb : kwb;
        const int nb = n0 & 1023;
        #pragma unroll
        for (int it = 0; it < 4; ++it)
            #pragma unroll
            for (int jt = 0; jt < 4; ++jt)
                #pragma unroll
                for (int r = 0; r < 4; ++r) {
                    int gm = m0 + wm*64 + it*16 + row0 + r;     // token
                    int gn = nb + wn*64 + jt*16 + col;          // h*64+d
                    int hh = gn >> 6, d = gn & 63;
                    int bb = gm >> 11, ss = gm & (SEQ - 1);
                    obuf[(((size_t)(bb*NH + hh))*SEQ + ss)*64 + d] = f2bf(acc[it][jt][r]);
                }
    }
}

// ---------------------------------------------------------------------------
// Splat weights from bf16 q (or k), head-major [(b*NH+h)*SEQ+s]*64.
// One block = 256 consecutive tokens of one (b,h); one thread per token.
// wout[(b*NH+h)*SEQ+s]*16+sp = exp(-0.5*|q-c_sp|^2 / s_sp^2) * sigmoid(amp_sp)
// ---------------------------------------------------------------------------
__global__ __launch_bounds__(256) void splat_kernel(
    const ushort* __restrict__ qk, ushort* __restrict__ wout,
    const float* __restrict__ centers, const float* __restrict__ lscales,
    const float* __restrict__ amps)
{
    __shared__ float Cs[16*64];
    __shared__ float Pr[48];          // [0,16): -0.5/s2, [16,32): amp, [32,48): cn
    const int tid = threadIdx.x;
    const int bh  = blockIdx.x >> 3;
    const int h   = bh & 15;
    const int s   = (blockIdx.x & 7) * 256 + tid;
    {
        float4 c4 = *(const float4*)(centers + (size_t)h*1024 + tid*4);
        *(float4*)(Cs + tid*4) = c4;
    }
    if (tid < 16) {
        float s2 = __expf(2.f * lscales[h*16 + tid]);
        Pr[tid]      = -0.5f / s2;
        Pr[16 + tid] = 1.f / (1.f + __expf(-amps[h*16 + tid]));
        const float* cp = centers + ((size_t)h*16 + tid)*64;
        float cn = 0.f;
        for (int i = 0; i < 64; ++i) cn += cp[i]*cp[i];
        Pr[32 + tid] = cn;
    }
    __syncthreads();

    float q[64];
    const ushort* qp = qk + ((size_t)bh*SEQ + s)*64;
    #pragma unroll
    for (int i = 0; i < 8; ++i) {
        short8 v = *(const short8*)(qp + i*8);
        #pragma unroll
        for (int j = 0; j < 8; ++j) q[i*8+j] = bf2f((ushort)v[j]);
    }
    float tn = 0.f;
    #pragma unroll
    for (int i = 0; i < 64; ++i) tn = fmaf(q[i], q[i], tn);

    ushort o16[16];
    #pragma unroll 4
    for (int sp = 0; sp < 16; ++sp) {
        const float* cp = Cs + sp*64;
        float cr = 0.f;
        #pragma unroll
        for (int i = 0; i < 64; ++i) cr = fmaf(q[i], cp[i], cr);
        float dq = tn - 2.f*cr + Pr[32 + sp];
        o16[sp] = f2bf(__expf(dq * Pr[sp]) * Pr[16 + sp]);
    }
    ushort* op = wout + ((size_t)bh*SEQ + s)*16;
    *(short8*)(op)     = *(short8*)(o16);
    *(short8*)(op + 8) = *(short8*)(o16 + 8);
}

// ---------------------------------------------------------------------------
// MFMA flash attention, v2:
//  - 512 threads / 8 waves per block; waves split into 2 groups (g = w>>2),
//    each group owns half the key range with private VT/P LDS buffers
//    -> 32 waves/CU (was 16), same barrier count per block.
//  - QK^T via mfma_f32_32x32x16_bf16 (K=16 exactly: no zero-padded half,
//    no masked lanes, 1 MFMA instead of 4). Wave (qh,kh) computes the
//    32q x 32k quadrant; C layout: col=query(l&31), row=key=(r&3)+8*(r>>2)+4*hi
//    -> each lane holds 4 runs of 4 consecutive keys for ONE query.
//  - P pack: v_perm truncation to bf16 (same numerics as before) -> one
//    ds_write_b64 per 4 keys (4 wide stores vs 16 scalar ds_write_b16).
//  - K fragments loaded directly from global (kw is L2-hot; drops KW
//    staging and its barrier dependency).
//  - End: group-1 partials added to group-0 via LDS, single epilogue.
// ---------------------------------------------------------------------------
__global__ __launch_bounds__(512) void attn_kernel(
    const ushort* __restrict__ qw, const ushort* __restrict__ kw,
    const ushort* __restrict__ vbt, ushort* __restrict__ hoh, ushort* __restrict__ hol)
{
    // [0,16K): VT[g]  (8KB each, [d][key] xor-swizzled 16B blocks)
    // [16K,32K): P[g] (8KB each, [64 q][64 key] bf16, xor-swizzled)
    __shared__ __align__(16) char smem[32768];
    const int tid = threadIdx.x;
    const int l    = tid & 63;
    const int w    = tid >> 6;        // 0..7
    const int g    = w >> 2;          // key-half group
    const int wq   = w & 3;           // wave-in-group
    const int qh   = wq >> 1;         // query 32-half (QK phase)
    const int kh   = wq & 1;          // key 32-half (QK phase)
    const int l31  = l & 31;
    const int hi   = l >> 5;
    const int qrow = l & 15;
    const int quad = l >> 4;
    const int bh = blockIdx.y;
    const int b = bh >> 4;
    const int h = bh & 15;
    const int s0 = blockIdx.x * 64;

    char*   VTg = smem + g*8192;
    ushort* Pg  = (ushort*)(smem + 16384 + g*8192);

    // Q fragment (B operand of 32x32x16): query qh*32+l31, k = hi*8..+8
    short8 qf = *(const short8*)(qw + ((size_t)bh*SEQ + s0 + qh*32 + l31)*16 + hi*8);

    const ushort* kwb = kw + ((size_t)bh*SEQ)*16;
    const ushort* vtb = vbt + ((size_t)(b*1024 + h*64))*SEQ;

    floatx4 accv[4] = {};
    floatx4 accz = {};
    floatx16 zero16 = {};
    short8 ones;
    #pragma unroll
    for (int i = 0; i < 8; ++i) ones[i] = (short)0x3F80;

    // V staging (per group, same swizzle as before, wq in place of w)
    const int vd0 = wq*16 + (l >> 3);
    const int vkb0 = (l & 7) ^ (vd0 & 7);
    const int vd1 = wq*16 + 8 + (l >> 3);
    const int vkb1 = (l & 7) ^ (vd1 & 7);

    // P write base: query pq, sub-offset hi*4 ushorts (=8B within 16B block)
    const int pq = qh*32 + l31;
    ushort* pwr = Pg + pq*64 + hi*4;
    const int pxor = (pq & 7) << 3;   // swizzle in ushort units

    for (int jt = 0; jt < 16; ++jt) {
        const int j0 = g*1024 + jt*64;
        __syncthreads();   // prev-iter VT/P reads complete before overwrite
        // K fragment (A operand) direct from global: key kh*32+l31, k=hi*8..+8
        short8 kf = *(const short8*)(kwb + (size_t)(j0 + kh*32 + l31)*16 + hi*8);
        // stage V^T tile for this group
        gload16(vtb + (size_t)vd0*SEQ + j0 + vkb0*8, VTg + (wq*2  )*1024);
        gload16(vtb + (size_t)vd1*SEQ + j0 + vkb1*8, VTg + (wq*2+1)*1024);

        // QK^T quadrant: C[key][query], keys kh*32.., queries qh*32..
        floatx16 sc = __builtin_amdgcn_mfma_f32_32x32x16_bf16(kf, qf, zero16, 0, 0, 0);

        // exp + truncate-pack to bf16, one b64 store per 4 consecutive keys
        #pragma unroll
        for (int u = 0; u < 4; ++u) {
            float e0 = __expf(sc[u*4+0]);
            float e1 = __expf(sc[u*4+1]);
            float e2 = __expf(sc[u*4+2]);
            float e3 = __expf(sc[u*4+3]);
            uint2 pv;
            pv.x = __builtin_amdgcn_perm(__float_as_uint(e1), __float_as_uint(e0), 0x07060302u);
            pv.y = __builtin_amdgcn_perm(__float_as_uint(e3), __float_as_uint(e2), 0x07060302u);
            int kblk = kh*4 + u;                 // 16B block index (keys k0 = kblk*8+4*hi)
            *(uint2*)(pwr + ((kblk*8) ^ pxor)) = pv;
        }
        __syncthreads();   // VT staged (vmcnt drain) + P written (all 4 waves)

        // PV: each wave 16 queries (wq*16..) x 64 d over the 64-key tile
        #pragma unroll
        for (int kc = 0; kc < 2; ++kc) {
            int kb = kc*4 + quad;
            short8 pa = *(const short8*)(Pg + (wq*16 + qrow)*64 + ((kb ^ (qrow & 7)) << 3));
            #pragma unroll
            for (int nt = 0; nt < 4; ++nt) {
                int d = nt*16 + qrow;
                short8 vb8 = *(const short8*)((ushort*)VTg + d*64 + ((kb ^ (d & 7)) << 3));
                accv[nt] = __builtin_amdgcn_mfma_f32_16x16x32_bf16(pa, vb8, accv[nt], 0, 0, 0);
            }
            accz = __builtin_amdgcn_mfma_f32_16x16x32_bf16(pa, ones, accz, 0, 0, 0);
        }
    }

    // cross-group combine: group 1 partials -> LDS, group 0 adds + epilogue
    __syncthreads();
    float* vb  = (float*)smem;            // 16KB, aliases VT[0..1] (dead)
    float* zbf = (float*)(smem + 16384);  // 256B, aliases P[0] (dead)
    if (g) {
        #pragma unroll
        for (int nt = 0; nt < 4; ++nt)
            #pragma unroll
            for (int r = 0; r < 4; ++r)
                vb[(wq*16 + quad*4 + r)*64 + nt*16 + qrow] = accv[nt][r];
        if (qrow == 0) {
            #pragma unroll
            for (int r = 0; r < 4; ++r) zbf[wq*16 + quad*4 + r] = accz[r];
        }
    }
    __syncthreads();
    if (!g) {
        #pragma unroll
        for (int r = 0; r < 4; ++r) {
            int qq = wq*16 + quad*4 + r;
            float z = accz[r] + zbf[qq];
            float inv = 1.0f / z;
            int s = s0 + qq;
            size_t base = ((size_t)(b*SEQ + s))*1024 + h*64;
            #pragma unroll
            for (int nt = 0; nt < 4; ++nt) {
                float val = (accv[nt][r] + vb[qq*64 + nt*16 + qrow]) * inv;
                ushort vh = f2bf(val);
                ushort vl = f2bf(val - bf2f(vh));
                hoh[base + nt*16 + qrow] = vh;
                hol[base + nt*16 + qrow] = vl;
            }
        }
    }
}

// ---------------------------------------------------------------------------
extern "C" void kernel_launch(void* const* d_in, const int* in_sizes, int n_in,
                              void* d_out, int out_size, void* d_ws, size_t ws_size,
                              hipStream_t stream)
{
    const float* x       = (const float*)d_in[0];
    const float* qkv_w   = (const float*)d_in[1];
    const float* out_w   = (const float*)d_in[2];
    const float* centers = (const float*)d_in[3];
    const float* lscales = (const float*)d_in[4];
    const float* amps    = (const float*)d_in[5];
    float* out  = (float*)d_out;                      // [B,S,D]
    float* traj = out + (size_t)NB*SEQ*DIM;           // [B,S,D]

    char* wsb = (char*)d_ws;                          // 40.03 MB total
    ushort* xh   = (ushort*)(wsb);                    // [0,8) MB  bf16 x hi
    ushort* xl   = (ushort*)(wsb + (8u<<20));         // [8,16) MB bf16 x lo
    ushort* wh   = (ushort*)(wsb + (16u<<20));        // [16,22) MB qkv_w hi (3072x1024)
    ushort* wlv  = (ushort*)(wsb + (22u<<20));        // [22,24) MB v-weight lo
    ushort* vbt  = (ushort*)(wsb + (24u<<20));        // [24,32) MB v^T bf16 [B,1024,S]
    float*  sbuf = (float*)(wsb + (40u<<20));         // 16 KB
    float*  invb = sbuf + 4096;                       // 16 KB
    // aliases (regions dead by the time they're written):
    ushort* qbuf = xl;                                // q bf16 head-major (xl dead after vgemm)
    ushort* kbuf = (ushort*)(wsb + (32u<<20));        // k bf16 head-major, [32,40) free
    ushort* qwbh = wlv;                               // splat-q out (after vgemm)
    ushort* kwbh = wh + 2048*1024;                    // wh [20,22) dead after vgemm
    ushort* owh  = wh;                                // wh [16,18) dead after qkgemm
    ushort* owl  = wh + 1048576;                      // wh [18,20)
    ushort* hoh  = xh;                                // after qkgemm (attn writes)
    ushort* hol  = xl;                                // after splat-q consumed qbuf

    cvt_split_kernel<<<4096, 256, 0, stream>>>(x, xh, xl, 4194304);
    cvt_hi_kernel<<<3072, 256, 0, stream>>>(qkv_w, wh, 3145728);
    cvt_split_kernel<<<1024, 256, 0, stream>>>(qkv_w + 2097152, wh + 2097152, wlv, 1048576);
    traj_stats_kernel<<<1024, 256, 0, stream>>>(x, sbuf, invb);
    traj_kernel<<<NB*SEQ, 256, 0, stream>>>(x, sbuf, invb, traj);
    // v^T = Wv @ x^T  (split, bf16 transposed store [B,1024,S])
    mfma_gemm<1,2><<<dim3(32, 8), 256, 0, stream>>>(
        wh + 2048*1024, wlv, xh, xl, nullptr, 0, vbt, nullptr);
    // q,k projection (plain bf16), head-major bf16 out
    mfma_gemm<0,3><<<dim3(16, 32), 256, 0, stream>>>(
        xh, nullptr, wh, nullptr, nullptr, 0, qbuf, kbuf);
    // splat weights
    splat_kernel<<<256, 256, 0, stream>>>(qbuf, qwbh, centers, lscales, amps);
    splat_kernel<<<256, 256, 0, stream>>>(kbuf, kwbh, centers, lscales, amps);
    cvt_split_kernel<<<1024, 256, 0, stream>>>(out_w, owh, owl, 1048576);
    attn_kernel<<<dim3(32, 32), 512, 0, stream>>>(qwbh, kwbh, vbt, hoh, hol);
    // out = ho @ out_w^T  (split, fp32 out)
    mfma_gemm<1,0><<<dim3(8, 32), 256, 0, stream>>>(
        hoh, hol, owh, owl, out, 1024, nullptr, nullptr);
}

// Round 2
// 290.437 us; speedup vs baseline: 1.0610x; 1.0186x over previous
//
#include <hip/hip_runtime.h>
#include <math.h>

// Problem constants (B=2, S=2048, D=1024, H=16, hd=64, K=16)
#define SEQ 2048
#define DIM 1024
#define NB  2
#define NH  16

typedef __attribute__((ext_vector_type(8))) short short8;
typedef __attribute__((ext_vector_type(4))) float floatx4;
typedef __attribute__((ext_vector_type(16))) float floatx16;

__device__ __forceinline__ ushort f2bf(float f) {
    unsigned u = __float_as_uint(f);
    return (ushort)((u + 0x7FFFu + ((u >> 16) & 1u)) >> 16);
}
__device__ __forceinline__ float bf2f(ushort h) {
    return __uint_as_float(((unsigned)h) << 16);
}
// async global->LDS, 16B per lane; LDS dest = wave-uniform base + lane*16
__device__ __forceinline__ void gload16(const void* g, char* lds_base) {
    __builtin_amdgcn_global_load_lds(
        (const __attribute__((address_space(1))) void*)g,
        (__attribute__((address_space(3))) void*)lds_base, 16, 0, 0);
}
// packed f32x2 -> bf16x2 (RNE), low word = a
__device__ __forceinline__ unsigned cvtpk(float a, float b) {
    unsigned r;
    asm("v_cvt_pk_bf16_f32 %0, %1, %2" : "=v"(r) : "v"(a), "v"(b));
    return r;
}
// swap: a -> [a.lo32 | b.lo32], b -> [a.hi32 | b.hi32]
__device__ __forceinline__ void plswap(unsigned &a, unsigned &b) {
    asm("v_permlane32_swap_b32 %0, %1" : "+v"(a), "+v"(b));
}

// ---------------------------------------------------------------------------
// fp32 -> bf16 (hi only)
// ---------------------------------------------------------------------------
__global__ __launch_bounds__(256) void cvt_hi_kernel(
    const float* __restrict__ src, ushort* __restrict__ dst, int n)
{
    int i = (blockIdx.x * 256 + threadIdx.x) * 4;
    if (i >= n) return;
    float4 v = *(const float4*)(src + i);
    ushort4 o;
    o.x = f2bf(v.x); o.y = f2bf(v.y); o.z = f2bf(v.z); o.w = f2bf(v.w);
    *(ushort4*)(dst + i) = o;
}

// fp32 -> bf16 hi + lo (x ~= hi + lo, residual ~2^-17 relative)
__global__ __launch_bounds__(256) void cvt_split_kernel(
    const float* __restrict__ src, ushort* __restrict__ hi, ushort* __restrict__ lo, int n)
{
    int i = (blockIdx.x * 256 + threadIdx.x) * 4;
    if (i >= n) return;
    float4 v = *(const float4*)(src + i);
    ushort4 h, l;
    h.x = f2bf(v.x); l.x = f2bf(v.x - bf2f(h.x));
    h.y = f2bf(v.y); l.y = f2bf(v.y - bf2f(h.y));
    h.z = f2bf(v.z); l.z = f2bf(v.z - bf2f(h.z));
    h.w = f2bf(v.w); l.w = f2bf(v.w - bf2f(h.w));
    *(ushort4*)(hi + i) = h;
    *(ushort4*)(lo + i) = l;
}

// ---------------------------------------------------------------------------
// K1: per-diff stats
// ---------------------------------------------------------------------------
__global__ __launch_bounds__(256) void traj_stats_kernel(
    const float* __restrict__ x, float* __restrict__ sbuf, float* __restrict__ invbuf)
{
    const int wave = threadIdx.x >> 6;
    const int lane = threadIdx.x & 63;
    const int row  = blockIdx.x * 4 + wave;
    const int NR = NB * (SEQ - 1);
    if (row >= NR) return;
    const int b = row / (SEQ - 1);
    const int j = row - b * (SEQ - 1);
    const float* x0 = x + ((size_t)(b * SEQ + j)) * DIM;
    const float* x1 = x0 + DIM;
    float sum = 0.f;
    #pragma unroll
    for (int q = 0; q < 4; ++q) {
        int idx = q * 256 + lane * 4;
        float4 a = *(const float4*)(x0 + idx);
        float4 c = *(const float4*)(x1 + idx);
        float dx = c.x-a.x, dy = c.y-a.y, dz = c.z-a.z, dw = c.w-a.w;
        sum += dx*dx + dy*dy + dz*dz + dw*dw;
    }
    #pragma unroll
    for (int off = 32; off > 0; off >>= 1) sum += __shfl_down(sum, off);
    if (lane == 0) {
        float mag = sqrtf(sum);
        sbuf[row]   = tanhf(mag);
        invbuf[row] = 1.0f / fmaxf(mag, 1e-8f);
    }
}

// ---------------------------------------------------------------------------
// K2: traj combine (window <= 8)
// ---------------------------------------------------------------------------
__global__ __launch_bounds__(256) void traj_kernel(
    const float* __restrict__ x, const float* __restrict__ sbuf,
    const float* __restrict__ invbuf, float* __restrict__ traj_out)
{
    const int bp = blockIdx.x;
    const int b  = bp >> 11;
    const int p  = bp & (SEQ - 1);
    int ws = p - 8; if (ws < 0) ws = 0;
    const int wlen = p - ws;
    const float wsz = (float)((p - ws) > 1 ? (p - ws) : 1);
    const int base = b * (SEQ - 1) + ws;

    float Z = 0.f;
    for (int t = 0; t < wlen; ++t)
        Z += sbuf[base + t] * ((float)(t + 1) / wsz);
    const float scale = 1.0f / fmaxf(Z, 1e-8f);

    const int d0 = threadIdx.x * 4;
    const float* xb = x + ((size_t)(b * SEQ + ws)) * DIM + d0;
    float4 prev = *(const float4*)xb;
    float4 acc = make_float4(0.f,0.f,0.f,0.f);
    for (int t = 0; t < wlen; ++t) {
        xb += DIM;
        float4 cur = *(const float4*)xb;
        float cc = sbuf[base + t] * ((float)(t + 1) / wsz) * invbuf[base + t] * scale;
        acc.x += cc * (cur.x - prev.x);
        acc.y += cc * (cur.y - prev.y);
        acc.z += cc * (cur.z - prev.z);
        acc.w += cc * (cur.w - prev.w);
        prev = cur;
    }
    *(float4*)(traj_out + (size_t)bp * DIM + d0) = acc;
}

// ---------------------------------------------------------------------------
// MFMA bf16 GEMM, m97 structure: C[M,N] = A[M,1024] @ B[N,1024]^T.
// 128x128 tile, BK=32, 4 waves 2x2, each wave 64x64 via 4x4 of 16x16x32.
// SPLIT=1: A ~= Ah+Al, B ~= Bh+Bl; C = Ah·Bh + Ah·Bl + Al·Bh (fp32-ish).
// EPI=0: fp32 store to cout (ldc).
// EPI=2 (v^T): bf16 store to qwb[b][m][token&2047]  (vbt layout [B,1024,S]).
// EPI=3 (q/k): bf16 head-major store: n<1024 -> qwb, else kwb,
//              layout [(b*NH+h)*SEQ + s]*64 + d.
// ---------------------------------------------------------------------------
template<int SPLIT, int EPI>
__global__ __launch_bounds__(256) void mfma_gemm(
    const ushort* __restrict__ Ah, const ushort* __restrict__ Al,
    const ushort* __restrict__ Bh, const ushort* __restrict__ Bl,
    float* __restrict__ cout, int ldc,
    ushort* __restrict__ qwb, ushort* __restrict__ kwb)
{
    constexpr int SMEM = SPLIT ? 32768 : 16384;
    __shared__ char smem[SMEM];
    const int tid = threadIdx.x;
    const int l = tid & 63;
    const int w = tid >> 6;
    const int wm = w >> 1, wn = w & 1;
    const int n0 = blockIdx.x * 128;
    const int m0 = blockIdx.y * 128;

    char* a_h = smem;
    char* b_h = smem + 8192;
    char* a_l = smem + 16384;
    char* b_l = smem + 24576;

    const int srow = 32 * w + (l >> 2);
    const int scol = (l & 3) * 8;
    const ushort* Ahg = Ah + (size_t)(m0 + srow) * 1024 + scol;
    const ushort* Bhg = Bh + (size_t)(n0 + srow) * 1024 + scol;
    const ushort* Alg = SPLIT ? Al + (size_t)(m0 + srow) * 1024 + scol : nullptr;
    const ushort* Blg = SPLIT ? Bl + (size_t)(n0 + srow) * 1024 + scol : nullptr;

    floatx4 acc[4][4] = {};
    const int fr = l & 15;
    const int fq = (l >> 4) * 16;

    for (int kb = 0; kb < 1024; kb += 32) {
        if (kb) __syncthreads();
        gload16(Ahg + kb,             a_h + w*2048);
        gload16(Ahg + kb + 16*1024,   a_h + w*2048 + 1024);
        gload16(Bhg + kb,             b_h + w*2048);
        gload16(Bhg + kb + 16*1024,   b_h + w*2048 + 1024);
        if (SPLIT) {
            gload16(Alg + kb,           a_l + w*2048);
            gload16(Alg + kb + 16*1024, a_l + w*2048 + 1024);
            gload16(Blg + kb,           b_l + w*2048);
            gload16(Blg + kb + 16*1024, b_l + w*2048 + 1024);
        }
        __syncthreads();
        short8 fah[4], fbh[4], fal[4], fbl[4];
        #pragma unroll
        for (int t = 0; t < 4; ++t) {
            fah[t] = *(const short8*)(a_h + ((wm*64 + t*16 + fr) << 6) + fq);
            fbh[t] = *(const short8*)(b_h + ((wn*64 + t*16 + fr) << 6) + fq);
            if (SPLIT) {
                fal[t] = *(const short8*)(a_l + ((wm*64 + t*16 + fr) << 6) + fq);
                fbl[t] = *(const short8*)(b_l + ((wn*64 + t*16 + fr) << 6) + fq);
            }
        }
        #pragma unroll
        for (int it = 0; it < 4; ++it)
            #pragma unroll
            for (int jt = 0; jt < 4; ++jt) {
                acc[it][jt] = __builtin_amdgcn_mfma_f32_16x16x32_bf16(
                    fah[it], fbh[jt], acc[it][jt], 0, 0, 0);
                if (SPLIT) {
                    acc[it][jt] = __builtin_amdgcn_mfma_f32_16x16x32_bf16(
                        fah[it], fbl[jt], acc[it][jt], 0, 0, 0);
                    acc[it][jt] = __builtin_amdgcn_mfma_f32_16x16x32_bf16(
                        fal[it], fbh[jt], acc[it][jt], 0, 0, 0);
                }
            }
    }

    const int row0 = (l >> 4) * 4;   // C: row=(l>>4)*4+reg, col=l&15
    const int col  = l & 15;

    if (EPI == 0) {
        #pragma unroll
        for (int it = 0; it < 4; ++it)
            #pragma unroll
            for (int jt = 0; jt < 4; ++jt)
                #pragma unroll
                for (int r = 0; r < 4; ++r) {
                    int gm = m0 + wm*64 + it*16 + row0 + r;
                    int gn = n0 + wn*64 + jt*16 + col;
                    cout[(size_t)gm * ldc + gn] = acc[it][jt][r];
                }
    } else if (EPI == 2) {
        // transposed v store: rows m = h*64+d, cols n = token
        #pragma unroll
        for (int it = 0; it < 4; ++it)
            #pragma unroll
            for (int jt = 0; jt < 4; ++jt)
                #pragma unroll
                for (int r = 0; r < 4; ++r) {
                    int md = m0 + wm*64 + it*16 + row0 + r;
                    int t  = n0 + wn*64 + jt*16 + col;
                    int bb = t >> 11, ss = t & (SEQ - 1);
                    qwb[((size_t)bb << 21) + (size_t)md * SEQ + ss] = f2bf(acc[it][jt][r]);
                }
    } else {
        // q/k bf16 head-major store
        ushort* obuf = (n0 < 1024) ? qwb : kwb;
        const int nb = n0 & 1023;
        #pragma unroll
        for (int it = 0; it < 4; ++it)
            #pragma unroll
            for (int jt = 0; jt < 4; ++jt)
                #pragma unroll
                for (int r = 0; r < 4; ++r) {
                    int gm = m0 + wm*64 + it*16 + row0 + r;     // token
                    int gn = nb + wn*64 + jt*16 + col;          // h*64+d
                    int hh = gn >> 6, d = gn & 63;
                    int bb = gm >> 11, ss = gm & (SEQ - 1);
                    obuf[(((size_t)(bb*NH + hh))*SEQ + ss)*64 + d] = f2bf(acc[it][jt][r]);
                }
    }
}

// ---------------------------------------------------------------------------
// Splat weights from bf16 q (or k), head-major [(b*NH+h)*SEQ+s]*64.
// One block = 256 consecutive tokens of one (b,h); one thread per token.
// wout[(b*NH+h)*SEQ+s]*16+sp = exp(-0.5*|q-c_sp|^2 / s_sp^2) * sigmoid(amp_sp)
// ---------------------------------------------------------------------------
__global__ __launch_bounds__(256) void splat_kernel(
    const ushort* __restrict__ qk, ushort* __restrict__ wout,
    const float* __restrict__ centers, const float* __restrict__ lscales,
    const float* __restrict__ amps)
{
    __shared__ float Cs[16*64];
    __shared__ float Pr[48];          // [0,16): -0.5/s2, [16,32): amp, [32,48): cn
    const int tid = threadIdx.x;
    const int bh  = blockIdx.x >> 3;
    const int h   = bh & 15;
    const int s   = (blockIdx.x & 7) * 256 + tid;
    {
        float4 c4 = *(const float4*)(centers + (size_t)h*1024 + tid*4);
        *(float4*)(Cs + tid*4) = c4;
    }
    if (tid < 16) {
        float s2 = __expf(2.f * lscales[h*16 + tid]);
        Pr[tid]      = -0.5f / s2;
        Pr[16 + tid] = 1.f / (1.f + __expf(-amps[h*16 + tid]));
        const float* cp = centers + ((size_t)h*16 + tid)*64;
        float cn = 0.f;
        for (int i = 0; i < 64; ++i) cn += cp[i]*cp[i];
        Pr[32 + tid] = cn;
    }
    __syncthreads();

    float q[64];
    const ushort* qp = qk + ((size_t)bh*SEQ + s)*64;
    #pragma unroll
    for (int i = 0; i < 8; ++i) {
        short8 v = *(const short8*)(qp + i*8);
        #pragma unroll
        for (int j = 0; j < 8; ++j) q[i*8+j] = bf2f((ushort)v[j]);
    }
    float tn = 0.f;
    #pragma unroll
    for (int i = 0; i < 64; ++i) tn = fmaf(q[i], q[i], tn);

    ushort o16[16];
    #pragma unroll 4
    for (int sp = 0; sp < 16; ++sp) {
        const float* cp = Cs + sp*64;
        float cr = 0.f;
        #pragma unroll
        for (int i = 0; i < 64; ++i) cr = fmaf(q[i], cp[i], cr);
        float dq = tn - 2.f*cr + Pr[32 + sp];
        o16[sp] = f2bf(__expf(dq * Pr[sp]) * Pr[16 + sp]);
    }
    ushort* op = wout + ((size_t)bh*SEQ + s)*16;
    *(short8*)(op)     = *(short8*)(o16);
    *(short8*)(op + 8) = *(short8*)(o16 + 8);
}

// ---------------------------------------------------------------------------
// MFMA flash attention, v3: all-register P (no P LDS round-trip).
//  - 256 threads / 4 waves (qh, kh); each wave: QK quadrant [kh keys][qh qs]
//    via 1x mfma_32x32x16, then exp, then in-register redistribution to the
//    PV A-fragment via 8x v_cvt_pk_bf16_f32 + 4x v_permlane32_swap_b32
//    (T12 idiom): swap(pk(e0,e1),pk(e4,e5)) -> both fragment words.
//  - PV: 4x mfma_32x32x16 (V as B-operand: 8 consecutive tokens per lane,
//    ds_read_b128 from xor-swizzled double-buffered V tile).
//  - z via 15 f32 adds/tile + one permlane swap at the end (no ones-MFMA).
//  - ONE barrier per 64-key tile (write-after-read guard + stage drain);
//    V tile staged once per block (deduped), kf direct from global (L2-hot).
//  - End: kh=1 partials combined through LDS (aliases V buffers), kh=0
//    waves divide by z and store hi/lo.
// ---------------------------------------------------------------------------
__global__ __launch_bounds__(256, 4) void attn_kernel(
    const ushort* __restrict__ qw, const ushort* __restrict__ kw,
    const ushort* __restrict__ vbt, ushort* __restrict__ hoh, ushort* __restrict__ hol)
{
    // [0,16K): V^T double buffer (2 x 8KB, [64 d][8 blk of 16B], blk^=(d&7))
    // [16K,16K+512): z combine buffer
    __shared__ __align__(16) char smem[16384 + 512];
    const int tid = threadIdx.x;
    const int l   = tid & 63;
    const int w   = tid >> 6;        // 0..3
    const int qh  = w >> 1;
    const int kh  = w & 1;
    const int l31 = l & 31;
    const int hi  = l >> 5;
    const int bh = blockIdx.y;
    const int b = bh >> 4;
    const int h = bh & 15;
    const int s0 = blockIdx.x * 64;

    // Q fragment (B operand): query s0+qh*32+l31, splat k = hi*8..+8
    short8 qf = *(const short8*)(qw + ((size_t)bh*SEQ + s0 + qh*32 + l31)*16 + hi*8);

    // K fragment source (A operand), direct from global (L2-hot)
    const ushort* kfp = kw + ((size_t)bh*SEQ + kh*32 + l31)*16 + hi*8;
    const ushort* vtb = vbt + ((size_t)(b*1024 + h*64))*SEQ;

    // V stage sources (pre-swizzled global addr -> linear LDS dest)
    const int dA = w*16 + (l >> 3);
    const int dB = dA + 8;
    const ushort* vsA = vtb + (size_t)dA*SEQ + ((l & 7) ^ (dA & 7))*8;
    const ushort* vsB = vtb + (size_t)dB*SEQ + ((l & 7) ^ (dB & 7))*8;

    floatx16 acc0 = {}, acc1 = {};
    floatx16 zero16 = {};
    float zpart = 0.f;

    // prologue: stage tile 0 into buf 0, load kf for tile 0
    gload16(vsA, smem + w*2048);
    gload16(vsB, smem + w*2048 + 1024);
    short8 kf = *(const short8*)kfp;

    for (int jt = 0; jt < 32; ++jt) {
        __syncthreads();   // drains own vmcnt/lgkm: stage(jt) landed, reads of buf^1 done
        char* bufn = smem + ((jt + 1) & 1)*8192;
        if (jt < 31) {
            gload16(vsA + (jt + 1)*64, bufn + w*2048);
            gload16(vsB + (jt + 1)*64, bufn + w*2048 + 1024);
        }
        // QK^T quadrant: C[key][query], key=(r&3)+8*(r>>2)+4*hi (+kh*32), q=l31 (+qh*32)
        floatx16 sc = __builtin_amdgcn_mfma_f32_32x32x16_bf16(kf, qf, zero16, 0, 0, 0);
        if (jt < 31) kf = *(const short8*)(kfp + (jt + 1)*1024);

        float e[16];
        #pragma unroll
        for (int r = 0; r < 16; ++r) e[r] = __expf(sc[r]);
        float zs = 0.f;
        #pragma unroll
        for (int r = 0; r < 16; ++r) zs += e[r];
        zpart += zs;

        // pack to PV A-fragments (lane q=l31, k=8*hi+0..7)
        unsigned p0 = cvtpk(e[0],  e[1]),  p1 = cvtpk(e[2],  e[3]);
        unsigned p2 = cvtpk(e[4],  e[5]),  p3 = cvtpk(e[6],  e[7]);
        unsigned p4 = cvtpk(e[8],  e[9]),  p5 = cvtpk(e[10], e[11]);
        unsigned p6 = cvtpk(e[12], e[13]), p7 = cvtpk(e[14], e[15]);
        plswap(p0, p2); plswap(p1, p3);   // kseg0: keys kh*32 + 0..15
        plswap(p4, p6); plswap(p5, p7);   // kseg1: keys kh*32 + 16..31
        union { unsigned u[4]; short8 s; } ua, ub;
        ua.u[0] = p0; ua.u[1] = p1; ua.u[2] = p2; ua.u[3] = p3;
        ub.u[0] = p4; ub.u[1] = p5; ub.u[2] = p6; ub.u[3] = p7;

        // PV: O[q][d], V as B operand (lane: d col = l31 (+32*dt), 8 tokens)
        const ushort* buf = (const ushort*)(smem + (jt & 1)*8192);
        #pragma unroll
        for (int dt = 0; dt < 2; ++dt) {
            int row = dt*32 + l31;
            const ushort* vr = buf + row*64;
            int bk0 = (kh*4 + hi)     ^ (row & 7);
            int bk1 = (kh*4 + 2 + hi) ^ (row & 7);
            short8 vb0 = *(const short8*)(vr + bk0*8);
            short8 vb1 = *(const short8*)(vr + bk1*8);
            if (dt == 0) {
                acc0 = __builtin_amdgcn_mfma_f32_32x32x16_bf16(ua.s, vb0, acc0, 0, 0, 0);
                acc0 = __builtin_amdgcn_mfma_f32_32x32x16_bf16(ub.s, vb1, acc0, 0, 0, 0);
            } else {
                acc1 = __builtin_amdgcn_mfma_f32_32x32x16_bf16(ua.s, vb0, acc1, 0, 0, 0);
                acc1 = __builtin_amdgcn_mfma_f32_32x32x16_bf16(ub.s, vb1, acc1, 0, 0, 0);
            }
        }
    }

    __syncthreads();   // drain everything before aliasing V buffers

    float* cb = (float*)smem;              // [qh*32+q][64 d] f32 = 16KB
    float* zb = (float*)(smem + 16384);    // [kh][64] f32 = 512B

    // z across hi halves: both halves end with total for their q
    unsigned za = __float_as_uint(zpart), zc = za;
    plswap(za, zc);
    float zq = __uint_as_float(za) + __uint_as_float(zc);
    if (l31 == l) zb[kh*64 + qh*32 + l31] = zq;   // lanes 0..31 only

    if (kh) {
        #pragma unroll
        for (int r = 0; r < 16; ++r) {
            int q = (r & 3) + 8*(r >> 2) + 4*hi;
            cb[(qh*32 + q)*64 + l31]      = acc0[r];
            cb[(qh*32 + q)*64 + 32 + l31] = acc1[r];
        }
    }
    __syncthreads();
    if (!kh) {
        #pragma unroll
        for (int r = 0; r < 16; ++r) {
            int q = (r & 3) + 8*(r >> 2) + 4*hi;
            float zt = zb[qh*32 + q] + zb[64 + qh*32 + q];
            float inv = 1.0f / zt;
            int s = s0 + qh*32 + q;
            size_t base = ((size_t)(b*SEQ + s))*1024 + h*64;
            float v0 = (acc0[r] + cb[(qh*32 + q)*64 + l31])      * inv;
            float v1 = (acc1[r] + cb[(qh*32 + q)*64 + 32 + l31]) * inv;
            ushort h0 = f2bf(v0);
            ushort h1 = f2bf(v1);
            hoh[base + l31]      = h0;
            hol[base + l31]      = f2bf(v0 - bf2f(h0));
            hoh[base + 32 + l31] = h1;
            hol[base + 32 + l31] = f2bf(v1 - bf2f(h1));
        }
    }
}

// ---------------------------------------------------------------------------
extern "C" void kernel_launch(void* const* d_in, const int* in_sizes, int n_in,
                              void* d_out, int out_size, void* d_ws, size_t ws_size,
                              hipStream_t stream)
{
    const float* x       = (const float*)d_in[0];
    const float* qkv_w   = (const float*)d_in[1];
    const float* out_w   = (const float*)d_in[2];
    const float* centers = (const float*)d_in[3];
    const float* lscales = (const float*)d_in[4];
    const float* amps    = (const float*)d_in[5];
    float* out  = (float*)d_out;                      // [B,S,D]
    float* traj = out + (size_t)NB*SEQ*DIM;           // [B,S,D]

    char* wsb = (char*)d_ws;                          // 40.03 MB total
    ushort* xh   = (ushort*)(wsb);                    // [0,8) MB  bf16 x hi
    ushort* xl   = (ushort*)(wsb + (8u<<20));         // [8,16) MB bf16 x lo
    ushort* wh   = (ushort*)(wsb + (16u<<20));        // [16,22) MB qkv_w hi (3072x1024)
    ushort* wlv  = (ushort*)(wsb + (22u<<20));        // [22,24) MB v-weight lo
    ushort* vbt  = (ushort*)(wsb + (24u<<20));        // [24,32) MB v^T bf16 [B,1024,S]
    float*  sbuf = (float*)(wsb + (40u<<20));         // 16 KB
    float*  invb = sbuf + 4096;                       // 16 KB
    // aliases (regions dead by the time they're written):
    ushort* qbuf = xl;                                // q bf16 head-major (xl dead after vgemm)
    ushort* kbuf = (ushort*)(wsb + (32u<<20));        // k bf16 head-major, [32,40) free
    ushort* qwbh = wlv;                               // splat-q out (after vgemm)
    ushort* kwbh = wh + 2048*1024;                    // wh [20,22) dead after vgemm
    ushort* owh  = wh;                                // wh [16,18) dead after qkgemm
    ushort* owl  = wh + 1048576;                      // wh [18,20)
    ushort* hoh  = xh;                                // after qkgemm (attn writes)
    ushort* hol  = xl;                                // after splat-q consumed qbuf

    cvt_split_kernel<<<4096, 256, 0, stream>>>(x, xh, xl, 4194304);
    cvt_hi_kernel<<<3072, 256, 0, stream>>>(qkv_w, wh, 3145728);
    cvt_split_kernel<<<1024, 256, 0, stream>>>(qkv_w + 2097152, wh + 2097152, wlv, 1048576);
    traj_stats_kernel<<<1024, 256, 0, stream>>>(x, sbuf, invb);
    traj_kernel<<<NB*SEQ, 256, 0, stream>>>(x, sbuf, invb, traj);
    // v^T = Wv @ x^T  (split, bf16 transposed store [B,1024,S])
    mfma_gemm<1,2><<<dim3(32, 8), 256, 0, stream>>>(
        wh + 2048*1024, wlv, xh, xl, nullptr, 0, vbt, nullptr);
    // q,k projection (plain bf16), head-major bf16 out
    mfma_gemm<0,3><<<dim3(16, 32), 256, 0, stream>>>(
        xh, nullptr, wh, nullptr, nullptr, 0, qbuf, kbuf);
    // splat weights
    splat_kernel<<<256, 256, 0, stream>>>(qbuf, qwbh, centers, lscales, amps);
    splat_kernel<<<256, 256, 0, stream>>>(kbuf, kwbh, centers, lscales, amps);
    cvt_split_kernel<<<1024, 256, 0, stream>>>(out_w, owh, owl, 1048576);
    attn_kernel<<<dim3(32, 32), 256, 0, stream>>>(qwbh, kwbh, vbt, hoh, hol);
    // out = ho @ out_w^T  (split, fp32 out)
    mfma_gemm<1,0><<<dim3(8, 32), 256, 0, stream>>>(
        hoh, hol, owh, owl, out, 1024, nullptr, nullptr);
}

// Round 3
// 270.488 us; speedup vs baseline: 1.1393x; 1.0738x over previous
//
#include <hip/hip_runtime.h>
#include <math.h>

// Problem constants (B=2, S=2048, D=1024, H=16, hd=64, K=16)
#define SEQ 2048
#define DIM 1024
#define NB  2
#define NH  16

typedef __attribute__((ext_vector_type(8))) short short8;
typedef __attribute__((ext_vector_type(4))) float floatx4;
typedef __attribute__((ext_vector_type(16))) float floatx16;

__device__ __forceinline__ ushort f2bf(float f) {
    unsigned u = __float_as_uint(f);
    return (ushort)((u + 0x7FFFu + ((u >> 16) & 1u)) >> 16);
}
__device__ __forceinline__ float bf2f(ushort h) {
    return __uint_as_float(((unsigned)h) << 16);
}
// async global->LDS, 16B per lane; LDS dest = wave-uniform base + lane*16
__device__ __forceinline__ void gload16(const void* g, char* lds_base) {
    __builtin_amdgcn_global_load_lds(
        (const __attribute__((address_space(1))) void*)g,
        (__attribute__((address_space(3))) void*)lds_base, 16, 0, 0);
}
// packed f32x2 -> bf16x2 (RNE), low word = a
__device__ __forceinline__ unsigned cvtpk(float a, float b) {
    unsigned r;
    asm("v_cvt_pk_bf16_f32 %0, %1, %2" : "=v"(r) : "v"(a), "v"(b));
    return r;
}
// swap: a -> [a.lo32 | b.lo32], b -> [a.hi32 | b.hi32]
__device__ __forceinline__ void plswap(unsigned &a, unsigned &b) {
    asm("v_permlane32_swap_b32 %0, %1" : "+v"(a), "+v"(b));
}

// ---------------------------------------------------------------------------
// fp32 -> bf16 hi + lo (x ~= hi + lo, residual ~2^-17 relative)
// ---------------------------------------------------------------------------
__global__ __launch_bounds__(256) void cvt_split_kernel(
    const float* __restrict__ src, ushort* __restrict__ hi, ushort* __restrict__ lo, int n)
{
    int i = (blockIdx.x * 256 + threadIdx.x) * 4;
    if (i >= n) return;
    float4 v = *(const float4*)(src + i);
    ushort4 h, l;
    h.x = f2bf(v.x); l.x = f2bf(v.x - bf2f(h.x));
    h.y = f2bf(v.y); l.y = f2bf(v.y - bf2f(h.y));
    h.z = f2bf(v.z); l.z = f2bf(v.z - bf2f(h.z));
    h.w = f2bf(v.w); l.w = f2bf(v.w - bf2f(h.w));
    *(ushort4*)(hi + i) = h;
    *(ushort4*)(lo + i) = l;
}

// ---------------------------------------------------------------------------
// Fused front conversions (one launch):
//  blocks [0,4096):    x fp32 -> xh + xl (split), 4M elems
//  blocks [4096,6144): qkv_w q/k rows -> wh (hi only), 2M elems
//  blocks [6144,7168): qkv_w v rows   -> wh+2M (hi) + wlv (lo), 1M elems
// ---------------------------------------------------------------------------
__global__ __launch_bounds__(256) void cvt_front_kernel(
    const float* __restrict__ x, const float* __restrict__ qkv_w,
    ushort* __restrict__ xh, ushort* __restrict__ xl,
    ushort* __restrict__ wh, ushort* __restrict__ wlv)
{
    const int blk = blockIdx.x;
    if (blk < 4096) {
        int i = blk * 1024 + threadIdx.x * 4;
        float4 v = *(const float4*)(x + i);
        ushort4 h, l;
        h.x = f2bf(v.x); l.x = f2bf(v.x - bf2f(h.x));
        h.y = f2bf(v.y); l.y = f2bf(v.y - bf2f(h.y));
        h.z = f2bf(v.z); l.z = f2bf(v.z - bf2f(h.z));
        h.w = f2bf(v.w); l.w = f2bf(v.w - bf2f(h.w));
        *(ushort4*)(xh + i) = h;
        *(ushort4*)(xl + i) = l;
    } else if (blk < 6144) {
        int i = (blk - 4096) * 1024 + threadIdx.x * 4;
        float4 v = *(const float4*)(qkv_w + i);
        ushort4 o;
        o.x = f2bf(v.x); o.y = f2bf(v.y); o.z = f2bf(v.z); o.w = f2bf(v.w);
        *(ushort4*)(wh + i) = o;
    } else {
        int i = (blk - 6144) * 1024 + threadIdx.x * 4;
        float4 v = *(const float4*)(qkv_w + 2097152 + i);
        ushort4 h, l;
        h.x = f2bf(v.x); l.x = f2bf(v.x - bf2f(h.x));
        h.y = f2bf(v.y); l.y = f2bf(v.y - bf2f(h.y));
        h.z = f2bf(v.z); l.z = f2bf(v.z - bf2f(h.z));
        h.w = f2bf(v.w); l.w = f2bf(v.w - bf2f(h.w));
        *(ushort4*)(wh + 2097152 + i) = h;
        *(ushort4*)(wlv + i) = l;
    }
}

// ---------------------------------------------------------------------------
// K1: per-diff stats
// ---------------------------------------------------------------------------
__global__ __launch_bounds__(256) void traj_stats_kernel(
    const float* __restrict__ x, float* __restrict__ sbuf, float* __restrict__ invbuf)
{
    const int wave = threadIdx.x >> 6;
    const int lane = threadIdx.x & 63;
    const int row  = blockIdx.x * 4 + wave;
    const int NR = NB * (SEQ - 1);
    if (row >= NR) return;
    const int b = row / (SEQ - 1);
    const int j = row - b * (SEQ - 1);
    const float* x0 = x + ((size_t)(b * SEQ + j)) * DIM;
    const float* x1 = x0 + DIM;
    float sum = 0.f;
    #pragma unroll
    for (int q = 0; q < 4; ++q) {
        int idx = q * 256 + lane * 4;
        float4 a = *(const float4*)(x0 + idx);
        float4 c = *(const float4*)(x1 + idx);
        float dx = c.x-a.x, dy = c.y-a.y, dz = c.z-a.z, dw = c.w-a.w;
        sum += dx*dx + dy*dy + dz*dz + dw*dw;
    }
    #pragma unroll
    for (int off = 32; off > 0; off >>= 1) sum += __shfl_down(sum, off);
    if (lane == 0) {
        float mag = sqrtf(sum);
        sbuf[row]   = tanhf(mag);
        invbuf[row] = 1.0f / fmaxf(mag, 1e-8f);
    }
}

// ---------------------------------------------------------------------------
// K2: traj combine (window <= 8)
// ---------------------------------------------------------------------------
__global__ __launch_bounds__(256) void traj_kernel(
    const float* __restrict__ x, const float* __restrict__ sbuf,
    const float* __restrict__ invbuf, float* __restrict__ traj_out)
{
    const int bp = blockIdx.x;
    const int b  = bp >> 11;
    const int p  = bp & (SEQ - 1);
    int ws = p - 8; if (ws < 0) ws = 0;
    const int wlen = p - ws;
    const float wsz = (float)((p - ws) > 1 ? (p - ws) : 1);
    const int base = b * (SEQ - 1) + ws;

    float Z = 0.f;
    for (int t = 0; t < wlen; ++t)
        Z += sbuf[base + t] * ((float)(t + 1) / wsz);
    const float scale = 1.0f / fmaxf(Z, 1e-8f);

    const int d0 = threadIdx.x * 4;
    const float* xb = x + ((size_t)(b * SEQ + ws)) * DIM + d0;
    float4 prev = *(const float4*)xb;
    float4 acc = make_float4(0.f,0.f,0.f,0.f);
    for (int t = 0; t < wlen; ++t) {
        xb += DIM;
        float4 cur = *(const float4*)xb;
        float cc = sbuf[base + t] * ((float)(t + 1) / wsz) * invbuf[base + t] * scale;
        acc.x += cc * (cur.x - prev.x);
        acc.y += cc * (cur.y - prev.y);
        acc.z += cc * (cur.z - prev.z);
        acc.w += cc * (cur.w - prev.w);
        prev = cur;
    }
    *(float4*)(traj_out + (size_t)bp * DIM + d0) = acc;
}

// ---------------------------------------------------------------------------
// MFMA bf16 GEMM: C[M,N] = A[M,1024] @ B[N,1024]^T.  Tile 128 x BN, BK=32,
// 4 waves 2x2 (wave tile 64 x BN/2), 16x16x32 MFMAs.
// BN=128: m97 geometry (256-block grids). BN=64: half-N tile -> 2x blocks,
// used for the SPLIT GEMMs whose natural grid is only 256 (1 block/CU).
// SPLIT=1: A ~= Ah+Al, B ~= Bh+Bl; C = Ah·Bh + Ah·Bl + Al·Bh (fp32-ish).
// EPI=0: fp32 store to cout (ldc).
// EPI=2 (v^T): bf16 store to qwb[b][m][token&2047]  (vbt layout [B,1024,S]).
// EPI=3 (q/k): bf16 head-major store: n<1024 -> qwb, else kwb,
//              layout [(b*NH+h)*SEQ + s]*64 + d.
// ---------------------------------------------------------------------------
template<int SPLIT, int EPI, int BN>
__global__ __launch_bounds__(256) void mfma_gemm(
    const ushort* __restrict__ Ah, const ushort* __restrict__ Al,
    const ushort* __restrict__ Bh, const ushort* __restrict__ Bl,
    float* __restrict__ cout, int ldc,
    ushort* __restrict__ qwb, ushort* __restrict__ kwb)
{
    constexpr int JT   = BN / 32;                    // N frags per wave
    constexpr int BSZ  = BN * 64;                    // B tile bytes (BN rows x 64B)
    constexpr int HALF = 8192 + BSZ;                 // one precision level (A+B)
    constexpr int SMEM = (SPLIT ? 2 : 1) * HALF;
    __shared__ __align__(16) char smem[SMEM];
    const int tid = threadIdx.x;
    const int l = tid & 63;
    const int w = tid >> 6;
    const int wm = w >> 1, wn = w & 1;
    const int n0 = blockIdx.x * BN;
    const int m0 = blockIdx.y * 128;

    char* a_h = smem;
    char* b_h = smem + 8192;
    char* a_l = smem + HALF;
    char* b_l = smem + HALF + 8192;

    const int srowA = 32 * w + (l >> 2);
    const int srowB = (BN == 128 ? 32 * w : 16 * w) + (l >> 2);
    const int scol  = (l & 3) * 8;
    const ushort* Ahg = Ah + (size_t)(m0 + srowA) * 1024 + scol;
    const ushort* Bhg = Bh + (size_t)(n0 + srowB) * 1024 + scol;
    const ushort* Alg = SPLIT ? Al + (size_t)(m0 + srowA) * 1024 + scol : nullptr;
    const ushort* Blg = SPLIT ? Bl + (size_t)(n0 + srowB) * 1024 + scol : nullptr;

    floatx4 acc[4][JT] = {};
    const int fr = l & 15;
    const int fq = (l >> 4) * 16;

    for (int kb = 0; kb < 1024; kb += 32) {
        if (kb) __syncthreads();
        gload16(Ahg + kb,             a_h + w*2048);
        gload16(Ahg + kb + 16*1024,   a_h + w*2048 + 1024);
        if (BN == 128) {
            gload16(Bhg + kb,             b_h + w*2048);
            gload16(Bhg + kb + 16*1024,   b_h + w*2048 + 1024);
        } else {
            gload16(Bhg + kb,             b_h + w*1024);
        }
        if (SPLIT) {
            gload16(Alg + kb,           a_l + w*2048);
            gload16(Alg + kb + 16*1024, a_l + w*2048 + 1024);
            if (BN == 128) {
                gload16(Blg + kb,           b_l + w*2048);
                gload16(Blg + kb + 16*1024, b_l + w*2048 + 1024);
            } else {
                gload16(Blg + kb,           b_l + w*1024);
            }
        }
        __syncthreads();
        short8 fah[4], fbh[JT], fal[4], fbl[JT];
        #pragma unroll
        for (int t = 0; t < 4; ++t) {
            fah[t] = *(const short8*)(a_h + ((wm*64 + t*16 + fr) << 6) + fq);
            if (SPLIT)
                fal[t] = *(const short8*)(a_l + ((wm*64 + t*16 + fr) << 6) + fq);
        }
        #pragma unroll
        for (int t = 0; t < JT; ++t) {
            fbh[t] = *(const short8*)(b_h + ((wn*(BN/2) + t*16 + fr) << 6) + fq);
            if (SPLIT)
                fbl[t] = *(const short8*)(b_l + ((wn*(BN/2) + t*16 + fr) << 6) + fq);
        }
        #pragma unroll
        for (int it = 0; it < 4; ++it)
            #pragma unroll
            for (int jt = 0; jt < JT; ++jt) {
                acc[it][jt] = __builtin_amdgcn_mfma_f32_16x16x32_bf16(
                    fah[it], fbh[jt], acc[it][jt], 0, 0, 0);
                if (SPLIT) {
                    acc[it][jt] = __builtin_amdgcn_mfma_f32_16x16x32_bf16(
                        fah[it], fbl[jt], acc[it][jt], 0, 0, 0);
                    acc[it][jt] = __builtin_amdgcn_mfma_f32_16x16x32_bf16(
                        fal[it], fbh[jt], acc[it][jt], 0, 0, 0);
                }
            }
    }

    const int row0 = (l >> 4) * 4;   // C: row=(l>>4)*4+reg, col=l&15
    const int col  = l & 15;

    if (EPI == 0) {
        #pragma unroll
        for (int it = 0; it < 4; ++it)
            #pragma unroll
            for (int jt = 0; jt < JT; ++jt)
                #pragma unroll
                for (int r = 0; r < 4; ++r) {
                    int gm = m0 + wm*64 + it*16 + row0 + r;
                    int gn = n0 + wn*(BN/2) + jt*16 + col;
                    cout[(size_t)gm * ldc + gn] = acc[it][jt][r];
                }
    } else if (EPI == 2) {
        // transposed v store: rows m = h*64+d, cols n = token
        #pragma unroll
        for (int it = 0; it < 4; ++it)
            #pragma unroll
            for (int jt = 0; jt < JT; ++jt)
                #pragma unroll
                for (int r = 0; r < 4; ++r) {
                    int md = m0 + wm*64 + it*16 + row0 + r;
                    int t  = n0 + wn*(BN/2) + jt*16 + col;
                    int bb = t >> 11, ss = t & (SEQ - 1);
                    qwb[((size_t)bb << 21) + (size_t)md * SEQ + ss] = f2bf(acc[it][jt][r]);
                }
    } else {
        // q/k bf16 head-major store
        ushort* obuf = (n0 < 1024) ? qwb : kwb;
        const int nb = n0 & 1023;
        #pragma unroll
        for (int it = 0; it < 4; ++it)
            #pragma unroll
            for (int jt = 0; jt < JT; ++jt)
                #pragma unroll
                for (int r = 0; r < 4; ++r) {
                    int gm = m0 + wm*64 + it*16 + row0 + r;     // token
                    int gn = nb + wn*(BN/2) + jt*16 + col;      // h*64+d
                    int hh = gn >> 6, d = gn & 63;
                    int bb = gm >> 11, ss = gm & (SEQ - 1);
                    obuf[(((size_t)(bb*NH + hh))*SEQ + ss)*64 + d] = f2bf(acc[it][jt][r]);
                }
    }
}

// ---------------------------------------------------------------------------
// Splat weights from bf16 q AND k (one dispatch), head-major inputs.
// blocks [0,256): q -> wq ; blocks [256,512): k -> wk.
// One sub-block = 256 consecutive tokens of one (b,h); one thread per token.
// ---------------------------------------------------------------------------
__global__ __launch_bounds__(256) void splat_kernel(
    const ushort* __restrict__ qin, const ushort* __restrict__ kin,
    ushort* __restrict__ wq, ushort* __restrict__ wk,
    const float* __restrict__ centers, const float* __restrict__ lscales,
    const float* __restrict__ amps)
{
    __shared__ float Cs[16*64];
    __shared__ float Pr[48];          // [0,16): -0.5/s2, [16,32): amp, [32,48): cn
    const int tid = threadIdx.x;
    const int isK = blockIdx.x >> 8;
    const int bx  = blockIdx.x & 255;
    const ushort* qk = isK ? kin : qin;
    ushort* wout = isK ? wk : wq;
    const int bh  = bx >> 3;
    const int h   = bh & 15;
    const int s   = (bx & 7) * 256 + tid;
    {
        float4 c4 = *(const float4*)(centers + (size_t)h*1024 + tid*4);
        *(float4*)(Cs + tid*4) = c4;
    }
    if (tid < 16) {
        float s2 = __expf(2.f * lscales[h*16 + tid]);
        Pr[tid]      = -0.5f / s2;
        Pr[16 + tid] = 1.f / (1.f + __expf(-amps[h*16 + tid]));
        const float* cp = centers + ((size_t)h*16 + tid)*64;
        float cn = 0.f;
        for (int i = 0; i < 64; ++i) cn += cp[i]*cp[i];
        Pr[32 + tid] = cn;
    }
    __syncthreads();

    float q[64];
    const ushort* qp = qk + ((size_t)bh*SEQ + s)*64;
    #pragma unroll
    for (int i = 0; i < 8; ++i) {
        short8 v = *(const short8*)(qp + i*8);
        #pragma unroll
        for (int j = 0; j < 8; ++j) q[i*8+j] = bf2f((ushort)v[j]);
    }
    float tn = 0.f;
    #pragma unroll
    for (int i = 0; i < 64; ++i) tn = fmaf(q[i], q[i], tn);

    ushort o16[16];
    #pragma unroll 4
    for (int sp = 0; sp < 16; ++sp) {
        const float* cp = Cs + sp*64;
        float cr = 0.f;
        #pragma unroll
        for (int i = 0; i < 64; ++i) cr = fmaf(q[i], cp[i], cr);
        float dq = tn - 2.f*cr + Pr[32 + sp];
        o16[sp] = f2bf(__expf(dq * Pr[sp]) * Pr[16 + sp]);
    }
    ushort* op = wout + ((size_t)bh*SEQ + s)*16;
    *(short8*)(op)     = *(short8*)(o16);
    *(short8*)(op + 8) = *(short8*)(o16 + 8);
}

// ---------------------------------------------------------------------------
// MFMA flash attention, v3: all-register P (no P LDS round-trip).
// 256 threads / 4 waves (qh, kh); QK quadrant via 1x mfma_32x32x16, exp,
// in-register redistribution to PV A-fragment via cvt_pk + permlane32_swap;
// PV via 4x mfma_32x32x16 from xor-swizzled double-buffered V tile.
// One barrier per 64-key tile; kh-partials combined through LDS at the end.
// ---------------------------------------------------------------------------
__global__ __launch_bounds__(256, 4) void attn_kernel(
    const ushort* __restrict__ qw, const ushort* __restrict__ kw,
    const ushort* __restrict__ vbt, ushort* __restrict__ hoh, ushort* __restrict__ hol)
{
    // [0,16K): V^T double buffer (2 x 8KB, [64 d][8 blk of 16B], blk^=(d&7))
    // [16K,16K+512): z combine buffer
    __shared__ __align__(16) char smem[16384 + 512];
    const int tid = threadIdx.x;
    const int l   = tid & 63;
    const int w   = tid >> 6;        // 0..3
    const int qh  = w >> 1;
    const int kh  = w & 1;
    const int l31 = l & 31;
    const int hi  = l >> 5;
    const int bh = blockIdx.y;
    const int b = bh >> 4;
    const int h = bh & 15;
    const int s0 = blockIdx.x * 64;

    // Q fragment (B operand): query s0+qh*32+l31, splat k = hi*8..+8
    short8 qf = *(const short8*)(qw + ((size_t)bh*SEQ + s0 + qh*32 + l31)*16 + hi*8);

    // K fragment source (A operand), direct from global (L2-hot)
    const ushort* kfp = kw + ((size_t)bh*SEQ + kh*32 + l31)*16 + hi*8;
    const ushort* vtb = vbt + ((size_t)(b*1024 + h*64))*SEQ;

    // V stage sources (pre-swizzled global addr -> linear LDS dest)
    const int dA = w*16 + (l >> 3);
    const int dB = dA + 8;
    const ushort* vsA = vtb + (size_t)dA*SEQ + ((l & 7) ^ (dA & 7))*8;
    const ushort* vsB = vtb + (size_t)dB*SEQ + ((l & 7) ^ (dB & 7))*8;

    floatx16 acc0 = {}, acc1 = {};
    floatx16 zero16 = {};
    float zpart = 0.f;

    // prologue: stage tile 0 into buf 0, load kf for tile 0
    gload16(vsA, smem + w*2048);
    gload16(vsB, smem + w*2048 + 1024);
    short8 kf = *(const short8*)kfp;

    for (int jt = 0; jt < 32; ++jt) {
        __syncthreads();   // drains own vmcnt/lgkm: stage(jt) landed, reads of buf^1 done
        char* bufn = smem + ((jt + 1) & 1)*8192;
        if (jt < 31) {
            gload16(vsA + (jt + 1)*64, bufn + w*2048);
            gload16(vsB + (jt + 1)*64, bufn + w*2048 + 1024);
        }
        // QK^T quadrant: C[key][query], key=(r&3)+8*(r>>2)+4*hi (+kh*32), q=l31 (+qh*32)
        floatx16 sc = __builtin_amdgcn_mfma_f32_32x32x16_bf16(kf, qf, zero16, 0, 0, 0);
        if (jt < 31) kf = *(const short8*)(kfp + (jt + 1)*1024);

        float e[16];
        #pragma unroll
        for (int r = 0; r < 16; ++r) e[r] = __expf(sc[r]);
        float zs = 0.f;
        #pragma unroll
        for (int r = 0; r < 16; ++r) zs += e[r];
        zpart += zs;

        // pack to PV A-fragments (lane q=l31, k=8*hi+0..7)
        unsigned p0 = cvtpk(e[0],  e[1]),  p1 = cvtpk(e[2],  e[3]);
        unsigned p2 = cvtpk(e[4],  e[5]),  p3 = cvtpk(e[6],  e[7]);
        unsigned p4 = cvtpk(e[8],  e[9]),  p5 = cvtpk(e[10], e[11]);
        unsigned p6 = cvtpk(e[12], e[13]), p7 = cvtpk(e[14], e[15]);
        plswap(p0, p2); plswap(p1, p3);   // kseg0: keys kh*32 + 0..15
        plswap(p4, p6); plswap(p5, p7);   // kseg1: keys kh*32 + 16..31
        union { unsigned u[4]; short8 s; } ua, ub;
        ua.u[0] = p0; ua.u[1] = p1; ua.u[2] = p2; ua.u[3] = p3;
        ub.u[0] = p4; ub.u[1] = p5; ub.u[2] = p6; ub.u[3] = p7;

        // PV: O[q][d], V as B operand (lane: d col = l31 (+32*dt), 8 tokens)
        const ushort* buf = (const ushort*)(smem + (jt & 1)*8192);
        #pragma unroll
        for (int dt = 0; dt < 2; ++dt) {
            int row = dt*32 + l31;
            const ushort* vr = buf + row*64;
            int bk0 = (kh*4 + hi)     ^ (row & 7);
            int bk1 = (kh*4 + 2 + hi) ^ (row & 7);
            short8 vb0 = *(const short8*)(vr + bk0*8);
            short8 vb1 = *(const short8*)(vr + bk1*8);
            if (dt == 0) {
                acc0 = __builtin_amdgcn_mfma_f32_32x32x16_bf16(ua.s, vb0, acc0, 0, 0, 0);
                acc0 = __builtin_amdgcn_mfma_f32_32x32x16_bf16(ub.s, vb1, acc0, 0, 0, 0);
            } else {
                acc1 = __builtin_amdgcn_mfma_f32_32x32x16_bf16(ua.s, vb0, acc1, 0, 0, 0);
                acc1 = __builtin_amdgcn_mfma_f32_32x32x16_bf16(ub.s, vb1, acc1, 0, 0, 0);
            }
        }
    }

    __syncthreads();   // drain everything before aliasing V buffers

    float* cb = (float*)smem;              // [qh*32+q][64 d] f32 = 16KB
    float* zb = (float*)(smem + 16384);    // [kh][64] f32 = 512B

    // z across hi halves: both halves end with total for their q
    unsigned za = __float_as_uint(zpart), zc = za;
    plswap(za, zc);
    float zq = __uint_as_float(za) + __uint_as_float(zc);
    if (l31 == l) zb[kh*64 + qh*32 + l31] = zq;   // lanes 0..31 only

    if (kh) {
        #pragma unroll
        for (int r = 0; r < 16; ++r) {
            int q = (r & 3) + 8*(r >> 2) + 4*hi;
            cb[(qh*32 + q)*64 + l31]      = acc0[r];
            cb[(qh*32 + q)*64 + 32 + l31] = acc1[r];
        }
    }
    __syncthreads();
    if (!kh) {
        #pragma unroll
        for (int r = 0; r < 16; ++r) {
            int q = (r & 3) + 8*(r >> 2) + 4*hi;
            float zt = zb[qh*32 + q] + zb[64 + qh*32 + q];
            float inv = 1.0f / zt;
            int s = s0 + qh*32 + q;
            size_t base = ((size_t)(b*SEQ + s))*1024 + h*64;
            float v0 = (acc0[r] + cb[(qh*32 + q)*64 + l31])      * inv;
            float v1 = (acc1[r] + cb[(qh*32 + q)*64 + 32 + l31]) * inv;
            ushort h0 = f2bf(v0);
            ushort h1 = f2bf(v1);
            hoh[base + l31]      = h0;
            hol[base + l31]      = f2bf(v0 - bf2f(h0));
            hoh[base + 32 + l31] = h1;
            hol[base + 32 + l31] = f2bf(v1 - bf2f(h1));
        }
    }
}

// ---------------------------------------------------------------------------
extern "C" void kernel_launch(void* const* d_in, const int* in_sizes, int n_in,
                              void* d_out, int out_size, void* d_ws, size_t ws_size,
                              hipStream_t stream)
{
    const float* x       = (const float*)d_in[0];
    const float* qkv_w   = (const float*)d_in[1];
    const float* out_w   = (const float*)d_in[2];
    const float* centers = (const float*)d_in[3];
    const float* lscales = (const float*)d_in[4];
    const float* amps    = (const float*)d_in[5];
    float* out  = (float*)d_out;                      // [B,S,D]
    float* traj = out + (size_t)NB*SEQ*DIM;           // [B,S,D]

    char* wsb = (char*)d_ws;                          // 40.03 MB total
    ushort* xh   = (ushort*)(wsb);                    // [0,8) MB  bf16 x hi
    ushort* xl   = (ushort*)(wsb + (8u<<20));         // [8,16) MB bf16 x lo
    ushort* wh   = (ushort*)(wsb + (16u<<20));        // [16,22) MB qkv_w hi (3072x1024)
    ushort* wlv  = (ushort*)(wsb + (22u<<20));        // [22,24) MB v-weight lo
    ushort* vbt  = (ushort*)(wsb + (24u<<20));        // [24,32) MB v^T bf16 [B,1024,S]
    float*  sbuf = (float*)(wsb + (40u<<20));         // 16 KB
    float*  invb = sbuf + 4096;                       // 16 KB
    // aliases (regions dead by the time they're written):
    ushort* qbuf = xl;                                // q bf16 head-major (xl dead after vgemm)
    ushort* kbuf = (ushort*)(wsb + (32u<<20));        // k bf16 head-major, [32,40) free
    ushort* qwbh = wlv;                               // splat-q out (after vgemm)
    ushort* kwbh = wh + 2048*1024;                    // wh [20,22) dead after vgemm
    ushort* owh  = wh;                                // wh [16,18) dead after qkgemm
    ushort* owl  = wh + 1048576;                      // wh [18,20)
    ushort* hoh  = xh;                                // after qkgemm (attn writes)
    ushort* hol  = xl;                                // after splat-q consumed qbuf

    cvt_front_kernel<<<7168, 256, 0, stream>>>(x, qkv_w, xh, xl, wh, wlv);
    traj_stats_kernel<<<1024, 256, 0, stream>>>(x, sbuf, invb);
    traj_kernel<<<NB*SEQ, 256, 0, stream>>>(x, sbuf, invb, traj);
    // v^T = Wv @ x^T  (split, bf16 transposed store [B,1024,S]), BN=64 -> 512 blocks
    mfma_gemm<1,2,64><<<dim3(64, 8), 256, 0, stream>>>(
        wh + 2048*1024, wlv, xh, xl, nullptr, 0, vbt, nullptr);
    // q,k projection (plain bf16), head-major bf16 out, BN=128 (512 blocks already)
    mfma_gemm<0,3,128><<<dim3(16, 32), 256, 0, stream>>>(
        xh, nullptr, wh, nullptr, nullptr, 0, qbuf, kbuf);
    // splat weights (q and k in one dispatch)
    splat_kernel<<<512, 256, 0, stream>>>(qbuf, kbuf, qwbh, kwbh, centers, lscales, amps);
    cvt_split_kernel<<<1024, 256, 0, stream>>>(out_w, owh, owl, 1048576);
    attn_kernel<<<dim3(32, 32), 256, 0, stream>>>(qwbh, kwbh, vbt, hoh, hol);
    // out = ho @ out_w^T  (split, fp32 out), BN=64 -> 512 blocks
    mfma_gemm<1,0,64><<<dim3(16, 32), 256, 0, stream>>>(
        hoh, hol, owh, owl, out, 1024, nullptr, nullptr);
}

// Round 4
// 245.786 us; speedup vs baseline: 1.2538x; 1.1005x over previous
//
#include <hip/hip_runtime.h>
#include <math.h>

// Problem constants (B=2, S=2048, D=1024, H=16, hd=64, K=16)
#define SEQ 2048
#define DIM 1024
#define NB  2
#define NH  16

typedef __attribute__((ext_vector_type(8))) short short8;
typedef __attribute__((ext_vector_type(4))) float floatx4;
typedef __attribute__((ext_vector_type(16))) float floatx16;

__device__ __forceinline__ ushort f2bf(float f) {
    unsigned u = __float_as_uint(f);
    return (ushort)((u + 0x7FFFu + ((u >> 16) & 1u)) >> 16);
}
__device__ __forceinline__ float bf2f(ushort h) {
    return __uint_as_float(((unsigned)h) << 16);
}
// async global->LDS, 16B per lane; LDS dest = wave-uniform base + lane*16
__device__ __forceinline__ void gload16(const void* g, char* lds_base) {
    __builtin_amdgcn_global_load_lds(
        (const __attribute__((address_space(1))) void*)g,
        (__attribute__((address_space(3))) void*)lds_base, 16, 0, 0);
}
// packed f32x2 -> bf16x2 (RNE), low word = a
__device__ __forceinline__ unsigned cvtpk(float a, float b) {
    unsigned r;
    asm("v_cvt_pk_bf16_f32 %0, %1, %2" : "=v"(r) : "v"(a), "v"(b));
    return r;
}
// swap: a -> [a.lo32 | b.lo32], b -> [a.hi32 | b.hi32]
__device__ __forceinline__ void plswap(unsigned &a, unsigned &b) {
    asm("v_permlane32_swap_b32 %0, %1" : "+v"(a), "+v"(b));
}

// ---------------------------------------------------------------------------
// Dispatch A: fused front conversions + traj stats (all depend only on inputs)
//  blocks [0,4096):    x fp32 -> xh + xl (split)
//  blocks [4096,6144): qkv_w q/k rows -> wh (hi only)
//  blocks [6144,7168): qkv_w v rows   -> wh+2M (hi) + wlv (lo)
//  blocks [7168,8192): traj stats (4 diff-rows per block)
// ---------------------------------------------------------------------------
__global__ __launch_bounds__(256) void front_kernel(
    const float* __restrict__ x, const float* __restrict__ qkv_w,
    ushort* __restrict__ xh, ushort* __restrict__ xl,
    ushort* __restrict__ wh, ushort* __restrict__ wlv,
    float* __restrict__ sbuf, float* __restrict__ invbuf)
{
    const int blk = blockIdx.x;
    if (blk < 4096) {
        int i = blk * 1024 + threadIdx.x * 4;
        float4 v = *(const float4*)(x + i);
        ushort4 h, l;
        h.x = f2bf(v.x); l.x = f2bf(v.x - bf2f(h.x));
        h.y = f2bf(v.y); l.y = f2bf(v.y - bf2f(h.y));
        h.z = f2bf(v.z); l.z = f2bf(v.z - bf2f(h.z));
        h.w = f2bf(v.w); l.w = f2bf(v.w - bf2f(h.w));
        *(ushort4*)(xh + i) = h;
        *(ushort4*)(xl + i) = l;
    } else if (blk < 6144) {
        int i = (blk - 4096) * 1024 + threadIdx.x * 4;
        float4 v = *(const float4*)(qkv_w + i);
        ushort4 o;
        o.x = f2bf(v.x); o.y = f2bf(v.y); o.z = f2bf(v.z); o.w = f2bf(v.w);
        *(ushort4*)(wh + i) = o;
    } else if (blk < 7168) {
        int i = (blk - 6144) * 1024 + threadIdx.x * 4;
        float4 v = *(const float4*)(qkv_w + 2097152 + i);
        ushort4 h, l;
        h.x = f2bf(v.x); l.x = f2bf(v.x - bf2f(h.x));
        h.y = f2bf(v.y); l.y = f2bf(v.y - bf2f(h.y));
        h.z = f2bf(v.z); l.z = f2bf(v.z - bf2f(h.z));
        h.w = f2bf(v.w); l.w = f2bf(v.w - bf2f(h.w));
        *(ushort4*)(wh + 2097152 + i) = h;
        *(ushort4*)(wlv + i) = l;
    } else {
        const int wave = threadIdx.x >> 6;
        const int lane = threadIdx.x & 63;
        const int row  = (blk - 7168) * 4 + wave;
        const int NR = NB * (SEQ - 1);
        if (row >= NR) return;
        const int b = row / (SEQ - 1);
        const int j = row - b * (SEQ - 1);
        const float* x0 = x + ((size_t)(b * SEQ + j)) * DIM;
        const float* x1 = x0 + DIM;
        float sum = 0.f;
        #pragma unroll
        for (int q = 0; q < 4; ++q) {
            int idx = q * 256 + lane * 4;
            float4 a = *(const float4*)(x0 + idx);
            float4 c = *(const float4*)(x1 + idx);
            float dx = c.x-a.x, dy = c.y-a.y, dz = c.z-a.z, dw = c.w-a.w;
            sum += dx*dx + dy*dy + dz*dz + dw*dw;
        }
        #pragma unroll
        for (int off = 32; off > 0; off >>= 1) sum += __shfl_down(sum, off);
        if (lane == 0) {
            float mag = sqrtf(sum);
            sbuf[row]   = tanhf(mag);
            invbuf[row] = 1.0f / fmaxf(mag, 1e-8f);
        }
    }
}

// ---------------------------------------------------------------------------
// traj combine body (window <= 8), one block per (b, pos)
// ---------------------------------------------------------------------------
__device__ __forceinline__ void traj_body(
    int bp, const float* __restrict__ x, const float* __restrict__ sbuf,
    const float* __restrict__ invbuf, float* __restrict__ traj_out)
{
    const int b  = bp >> 11;
    const int p  = bp & (SEQ - 1);
    int ws = p - 8; if (ws < 0) ws = 0;
    const int wlen = p - ws;
    const float wsz = (float)((p - ws) > 1 ? (p - ws) : 1);
    const int base = b * (SEQ - 1) + ws;

    float Z = 0.f;
    for (int t = 0; t < wlen; ++t)
        Z += sbuf[base + t] * ((float)(t + 1) / wsz);
    const float scale = 1.0f / fmaxf(Z, 1e-8f);

    const int d0 = threadIdx.x * 4;
    const float* xb = x + ((size_t)(b * SEQ + ws)) * DIM + d0;
    float4 prev = *(const float4*)xb;
    float4 acc = make_float4(0.f,0.f,0.f,0.f);
    for (int t = 0; t < wlen; ++t) {
        xb += DIM;
        float4 cur = *(const float4*)xb;
        float cc = sbuf[base + t] * ((float)(t + 1) / wsz) * invbuf[base + t] * scale;
        acc.x += cc * (cur.x - prev.x);
        acc.y += cc * (cur.y - prev.y);
        acc.z += cc * (cur.z - prev.z);
        acc.w += cc * (cur.w - prev.w);
        prev = cur;
    }
    *(float4*)(traj_out + (size_t)bp * DIM + d0) = acc;
}

// ---------------------------------------------------------------------------
// MFMA bf16 GEMM body: C[M,N] = A[M,1024] @ B[N,1024]^T.  Tile 128 x BN,
// BK=32, 4 waves 2x2 (wave tile 64 x BN/2), 16x16x32 MFMAs.
// SPLIT=1: A ~= Ah+Al, B ~= Bh+Bl; C = Ah·Bh + Ah·Bl + Al·Bh (fp32-ish).
// EPI=0: fp32 store to cout (ldc).
// EPI=2 (v^T): bf16 store to qwb[b][m][token&2047]  (vbt layout [B,1024,S]).
// EPI=3 (q/k): bf16 head-major store: n<1024 -> qwb, else kwb,
//              layout [(b*NH+h)*SEQ + s]*64 + d.
// ---------------------------------------------------------------------------
template<int SPLIT, int EPI, int BN>
__device__ __forceinline__ void gemm_body(
    int bx, int by, char* smem,
    const ushort* __restrict__ Ah, const ushort* __restrict__ Al,
    const ushort* __restrict__ Bh, const ushort* __restrict__ Bl,
    float* __restrict__ cout, int ldc,
    ushort* __restrict__ qwb, ushort* __restrict__ kwb)
{
    constexpr int JT   = BN / 32;                    // N frags per wave
    constexpr int BSZ  = BN * 64;                    // B tile bytes (BN rows x 64B)
    constexpr int HALF = 8192 + BSZ;                 // one precision level (A+B)
    const int tid = threadIdx.x;
    const int l = tid & 63;
    const int w = tid >> 6;
    const int wm = w >> 1, wn = w & 1;
    const int n0 = bx * BN;
    const int m0 = by * 128;

    char* a_h = smem;
    char* b_h = smem + 8192;
    char* a_l = smem + HALF;
    char* b_l = smem + HALF + 8192;

    const int srowA = 32 * w + (l >> 2);
    const int srowB = (BN == 128 ? 32 * w : 16 * w) + (l >> 2);
    const int scol  = (l & 3) * 8;
    const ushort* Ahg = Ah + (size_t)(m0 + srowA) * 1024 + scol;
    const ushort* Bhg = Bh + (size_t)(n0 + srowB) * 1024 + scol;
    const ushort* Alg = SPLIT ? Al + (size_t)(m0 + srowA) * 1024 + scol : nullptr;
    const ushort* Blg = SPLIT ? Bl + (size_t)(n0 + srowB) * 1024 + scol : nullptr;

    floatx4 acc[4][JT] = {};
    const int fr = l & 15;
    const int fq = (l >> 4) * 16;

    for (int kb = 0; kb < 1024; kb += 32) {
        if (kb) __syncthreads();
        gload16(Ahg + kb,             a_h + w*2048);
        gload16(Ahg + kb + 16*1024,   a_h + w*2048 + 1024);
        if (BN == 128) {
            gload16(Bhg + kb,             b_h + w*2048);
            gload16(Bhg + kb + 16*1024,   b_h + w*2048 + 1024);
        } else {
            gload16(Bhg + kb,             b_h + w*1024);
        }
        if (SPLIT) {
            gload16(Alg + kb,           a_l + w*2048);
            gload16(Alg + kb + 16*1024, a_l + w*2048 + 1024);
            if (BN == 128) {
                gload16(Blg + kb,           b_l + w*2048);
                gload16(Blg + kb + 16*1024, b_l + w*2048 + 1024);
            } else {
                gload16(Blg + kb,           b_l + w*1024);
            }
        }
        __syncthreads();
        short8 fah[4], fbh[JT], fal[4], fbl[JT];
        #pragma unroll
        for (int t = 0; t < 4; ++t) {
            fah[t] = *(const short8*)(a_h + ((wm*64 + t*16 + fr) << 6) + fq);
            if (SPLIT)
                fal[t] = *(const short8*)(a_l + ((wm*64 + t*16 + fr) << 6) + fq);
        }
        #pragma unroll
        for (int t = 0; t < JT; ++t) {
            fbh[t] = *(const short8*)(b_h + ((wn*(BN/2) + t*16 + fr) << 6) + fq);
            if (SPLIT)
                fbl[t] = *(const short8*)(b_l + ((wn*(BN/2) + t*16 + fr) << 6) + fq);
        }
        #pragma unroll
        for (int it = 0; it < 4; ++it)
            #pragma unroll
            for (int jt = 0; jt < JT; ++jt) {
                acc[it][jt] = __builtin_amdgcn_mfma_f32_16x16x32_bf16(
                    fah[it], fbh[jt], acc[it][jt], 0, 0, 0);
                if (SPLIT) {
                    acc[it][jt] = __builtin_amdgcn_mfma_f32_16x16x32_bf16(
                        fah[it], fbl[jt], acc[it][jt], 0, 0, 0);
                    acc[it][jt] = __builtin_amdgcn_mfma_f32_16x16x32_bf16(
                        fal[it], fbh[jt], acc[it][jt], 0, 0, 0);
                }
            }
    }

    const int row0 = (l >> 4) * 4;   // C: row=(l>>4)*4+reg, col=l&15
    const int col  = l & 15;

    if (EPI == 0) {
        #pragma unroll
        for (int it = 0; it < 4; ++it)
            #pragma unroll
            for (int jt = 0; jt < JT; ++jt)
                #pragma unroll
                for (int r = 0; r < 4; ++r) {
                    int gm = m0 + wm*64 + it*16 + row0 + r;
                    int gn = n0 + wn*(BN/2) + jt*16 + col;
                    cout[(size_t)gm * ldc + gn] = acc[it][jt][r];
                }
    } else if (EPI == 2) {
        // transposed v store: rows m = h*64+d, cols n = token
        #pragma unroll
        for (int it = 0; it < 4; ++it)
            #pragma unroll
            for (int jt = 0; jt < JT; ++jt)
                #pragma unroll
                for (int r = 0; r < 4; ++r) {
                    int md = m0 + wm*64 + it*16 + row0 + r;
                    int t  = n0 + wn*(BN/2) + jt*16 + col;
                    int bb = t >> 11, ss = t & (SEQ - 1);
                    qwb[((size_t)bb << 21) + (size_t)md * SEQ + ss] = f2bf(acc[it][jt][r]);
                }
    } else {
        // q/k bf16 head-major store
        ushort* obuf = (n0 < 1024) ? qwb : kwb;
        const int nb = n0 & 1023;
        #pragma unroll
        for (int it = 0; it < 4; ++it)
            #pragma unroll
            for (int jt = 0; jt < JT; ++jt)
                #pragma unroll
                for (int r = 0; r < 4; ++r) {
                    int gm = m0 + wm*64 + it*16 + row0 + r;     // token
                    int gn = nb + wn*(BN/2) + jt*16 + col;      // h*64+d
                    int hh = gn >> 6, d = gn & 63;
                    int bb = gm >> 11, ss = gm & (SEQ - 1);
                    obuf[(((size_t)(bb*NH + hh))*SEQ + ss)*64 + d] = f2bf(acc[it][jt][r]);
                }
    }
}

// Dispatch B: v^T GEMM (split, BN=64, 512 blocks) + traj[0,2048)
__global__ __launch_bounds__(256) void gemmV_traj_kernel(
    const ushort* __restrict__ Ah, const ushort* __restrict__ Al,
    const ushort* __restrict__ Bh, const ushort* __restrict__ Bl,
    ushort* __restrict__ vbt,
    const float* __restrict__ x, const float* __restrict__ sbuf,
    const float* __restrict__ invbuf, float* __restrict__ traj_out)
{
    __shared__ __align__(16) char smem[2 * (8192 + 64*64)];
    const int blk = blockIdx.x;
    if (blk < 512) {
        gemm_body<1,2,64>(blk & 63, blk >> 6, smem, Ah, Al, Bh, Bl,
                          nullptr, 0, vbt, nullptr);
    } else {
        traj_body(blk - 512, x, sbuf, invbuf, traj_out);
    }
}

// Dispatch C: q/k GEMM (plain, BN=128, 512 blocks) + traj[2048,4096)
__global__ __launch_bounds__(256) void gemmQK_traj_kernel(
    const ushort* __restrict__ Ah, const ushort* __restrict__ Bh,
    ushort* __restrict__ qbuf, ushort* __restrict__ kbuf,
    const float* __restrict__ x, const float* __restrict__ sbuf,
    const float* __restrict__ invbuf, float* __restrict__ traj_out)
{
    __shared__ __align__(16) char smem[8192 + 128*64];
    const int blk = blockIdx.x;
    if (blk < 512) {
        gemm_body<0,3,128>(blk & 15, blk >> 4, smem, Ah, nullptr, Bh, nullptr,
                           nullptr, 0, qbuf, kbuf);
    } else {
        traj_body(blk - 512 + 2048, x, sbuf, invbuf, traj_out);
    }
}

// Dispatch F: out GEMM (split, BN=64, fp32 out)
__global__ __launch_bounds__(256) void gemmO_kernel(
    const ushort* __restrict__ Ah, const ushort* __restrict__ Al,
    const ushort* __restrict__ Bh, const ushort* __restrict__ Bl,
    float* __restrict__ cout)
{
    __shared__ __align__(16) char smem[2 * (8192 + 64*64)];
    gemm_body<1,0,64>(blockIdx.x, blockIdx.y, smem, Ah, Al, Bh, Bl,
                      cout, 1024, nullptr, nullptr);
}

// ---------------------------------------------------------------------------
// Dispatch D: splat weights for q AND k + out_w hi/lo split (independent).
//  blocks [0,256): q -> wq ; [256,512): k -> wk ; [512,1536): out_w cvt.
// One splat sub-block = 256 consecutive tokens of one (b,h).
// ---------------------------------------------------------------------------
__global__ __launch_bounds__(256) void splat_cvt_kernel(
    const ushort* __restrict__ qin, const ushort* __restrict__ kin,
    ushort* __restrict__ wq, ushort* __restrict__ wk,
    const float* __restrict__ centers, const float* __restrict__ lscales,
    const float* __restrict__ amps,
    const float* __restrict__ out_w, ushort* __restrict__ owh, ushort* __restrict__ owl)
{
    __shared__ float Cs[16*64];
    __shared__ float Pr[48];          // [0,16): -0.5/s2, [16,32): amp, [32,48): cn
    const int tid = threadIdx.x;
    if (blockIdx.x >= 512) {
        int i = (blockIdx.x - 512) * 1024 + tid * 4;
        float4 v = *(const float4*)(out_w + i);
        ushort4 h, l;
        h.x = f2bf(v.x); l.x = f2bf(v.x - bf2f(h.x));
        h.y = f2bf(v.y); l.y = f2bf(v.y - bf2f(h.y));
        h.z = f2bf(v.z); l.z = f2bf(v.z - bf2f(h.z));
        h.w = f2bf(v.w); l.w = f2bf(v.w - bf2f(h.w));
        *(ushort4*)(owh + i) = h;
        *(ushort4*)(owl + i) = l;
        return;
    }
    const int isK = blockIdx.x >> 8;
    const int bx  = blockIdx.x & 255;
    const ushort* qk = isK ? kin : qin;
    ushort* wout = isK ? wk : wq;
    const int bh  = bx >> 3;
    const int h   = bh & 15;
    const int s   = (bx & 7) * 256 + tid;
    {
        float4 c4 = *(const float4*)(centers + (size_t)h*1024 + tid*4);
        *(float4*)(Cs + tid*4) = c4;
    }
    if (tid < 16) {
        float s2 = __expf(2.f * lscales[h*16 + tid]);
        Pr[tid]      = -0.5f / s2;
        Pr[16 + tid] = 1.f / (1.f + __expf(-amps[h*16 + tid]));
        const float* cp = centers + ((size_t)h*16 + tid)*64;
        float cn = 0.f;
        for (int i = 0; i < 64; ++i) cn += cp[i]*cp[i];
        Pr[32 + tid] = cn;
    }
    __syncthreads();

    float q[64];
    const ushort* qp = qk + ((size_t)bh*SEQ + s)*64;
    #pragma unroll
    for (int i = 0; i < 8; ++i) {
        short8 v = *(const short8*)(qp + i*8);
        #pragma unroll
        for (int j = 0; j < 8; ++j) q[i*8+j] = bf2f((ushort)v[j]);
    }
    float tn = 0.f;
    #pragma unroll
    for (int i = 0; i < 64; ++i) tn = fmaf(q[i], q[i], tn);

    ushort o16[16];
    #pragma unroll 4
    for (int sp = 0; sp < 16; ++sp) {
        const float* cp = Cs + sp*64;
        float cr = 0.f;
        #pragma unroll
        for (int i = 0; i < 64; ++i) cr = fmaf(q[i], cp[i], cr);
        float dq = tn - 2.f*cr + Pr[32 + sp];
        o16[sp] = f2bf(__expf(dq * Pr[sp]) * Pr[16 + sp]);
    }
    ushort* op = wout + ((size_t)bh*SEQ + s)*16;
    *(short8*)(op)     = *(short8*)(o16);
    *(short8*)(op + 8) = *(short8*)(o16 + 8);
}

// ---------------------------------------------------------------------------
// MFMA flash attention, v3: all-register P (no P LDS round-trip).
// 256 threads / 4 waves (qh, kh); QK quadrant via 1x mfma_32x32x16, exp,
// in-register redistribution to PV A-fragment via cvt_pk + permlane32_swap;
// PV via 4x mfma_32x32x16 from xor-swizzled double-buffered V tile.
// One barrier per 64-key tile; kh-partials combined through LDS at the end.
// ---------------------------------------------------------------------------
__global__ __launch_bounds__(256, 4) void attn_kernel(
    const ushort* __restrict__ qw, const ushort* __restrict__ kw,
    const ushort* __restrict__ vbt, ushort* __restrict__ hoh, ushort* __restrict__ hol)
{
    // [0,16K): V^T double buffer (2 x 8KB, [64 d][8 blk of 16B], blk^=(d&7))
    // [16K,16K+512): z combine buffer
    __shared__ __align__(16) char smem[16384 + 512];
    const int tid = threadIdx.x;
    const int l   = tid & 63;
    const int w   = tid >> 6;        // 0..3
    const int qh  = w >> 1;
    const int kh  = w & 1;
    const int l31 = l & 31;
    const int hi  = l >> 5;
    const int bh = blockIdx.y;
    const int b = bh >> 4;
    const int h = bh & 15;
    const int s0 = blockIdx.x * 64;

    // Q fragment (B operand): query s0+qh*32+l31, splat k = hi*8..+8
    short8 qf = *(const short8*)(qw + ((size_t)bh*SEQ + s0 + qh*32 + l31)*16 + hi*8);

    // K fragment source (A operand), direct from global (L2-hot)
    const ushort* kfp = kw + ((size_t)bh*SEQ + kh*32 + l31)*16 + hi*8;
    const ushort* vtb = vbt + ((size_t)(b*1024 + h*64))*SEQ;

    // V stage sources (pre-swizzled global addr -> linear LDS dest)
    const int dA = w*16 + (l >> 3);
    const int dB = dA + 8;
    const ushort* vsA = vtb + (size_t)dA*SEQ + ((l & 7) ^ (dA & 7))*8;
    const ushort* vsB = vtb + (size_t)dB*SEQ + ((l & 7) ^ (dB & 7))*8;

    floatx16 acc0 = {}, acc1 = {};
    floatx16 zero16 = {};
    float zpart = 0.f;

    // prologue: stage tile 0 into buf 0, load kf for tile 0
    gload16(vsA, smem + w*2048);
    gload16(vsB, smem + w*2048 + 1024);
    short8 kf = *(const short8*)kfp;

    for (int jt = 0; jt < 32; ++jt) {
        __syncthreads();   // drains own vmcnt/lgkm: stage(jt) landed, reads of buf^1 done
        char* bufn = smem + ((jt + 1) & 1)*8192;
        if (jt < 31) {
            gload16(vsA + (jt + 1)*64, bufn + w*2048);
            gload16(vsB + (jt + 1)*64, bufn + w*2048 + 1024);
        }
        // QK^T quadrant: C[key][query], key=(r&3)+8*(r>>2)+4*hi (+kh*32), q=l31 (+qh*32)
        floatx16 sc = __builtin_amdgcn_mfma_f32_32x32x16_bf16(kf, qf, zero16, 0, 0, 0);
        if (jt < 31) kf = *(const short8*)(kfp + (jt + 1)*1024);

        float e[16];
        #pragma unroll
        for (int r = 0; r < 16; ++r) e[r] = __expf(sc[r]);
        float zs = 0.f;
        #pragma unroll
        for (int r = 0; r < 16; ++r) zs += e[r];
        zpart += zs;

        // pack to PV A-fragments (lane q=l31, k=8*hi+0..7)
        unsigned p0 = cvtpk(e[0],  e[1]),  p1 = cvtpk(e[2],  e[3]);
        unsigned p2 = cvtpk(e[4],  e[5]),  p3 = cvtpk(e[6],  e[7]);
        unsigned p4 = cvtpk(e[8],  e[9]),  p5 = cvtpk(e[10], e[11]);
        unsigned p6 = cvtpk(e[12], e[13]), p7 = cvtpk(e[14], e[15]);
        plswap(p0, p2); plswap(p1, p3);   // kseg0: keys kh*32 + 0..15
        plswap(p4, p6); plswap(p5, p7);   // kseg1: keys kh*32 + 16..31
        union { unsigned u[4]; short8 s; } ua, ub;
        ua.u[0] = p0; ua.u[1] = p1; ua.u[2] = p2; ua.u[3] = p3;
        ub.u[0] = p4; ub.u[1] = p5; ub.u[2] = p6; ub.u[3] = p7;

        // PV: O[q][d], V as B operand (lane: d col = l31 (+32*dt), 8 tokens)
        const ushort* buf = (const ushort*)(smem + (jt & 1)*8192);
        #pragma unroll
        for (int dt = 0; dt < 2; ++dt) {
            int row = dt*32 + l31;
            const ushort* vr = buf + row*64;
            int bk0 = (kh*4 + hi)     ^ (row & 7);
            int bk1 = (kh*4 + 2 + hi) ^ (row & 7);
            short8 vb0 = *(const short8*)(vr + bk0*8);
            short8 vb1 = *(const short8*)(vr + bk1*8);
            if (dt == 0) {
                acc0 = __builtin_amdgcn_mfma_f32_32x32x16_bf16(ua.s, vb0, acc0, 0, 0, 0);
                acc0 = __builtin_amdgcn_mfma_f32_32x32x16_bf16(ub.s, vb1, acc0, 0, 0, 0);
            } else {
                acc1 = __builtin_amdgcn_mfma_f32_32x32x16_bf16(ua.s, vb0, acc1, 0, 0, 0);
                acc1 = __builtin_amdgcn_mfma_f32_32x32x16_bf16(ub.s, vb1, acc1, 0, 0, 0);
            }
        }
    }

    __syncthreads();   // drain everything before aliasing V buffers

    float* cb = (float*)smem;              // [qh*32+q][64 d] f32 = 16KB
    float* zb = (float*)(smem + 16384);    // [kh][64] f32 = 512B

    // z across hi halves: both halves end with total for their q
    unsigned za = __float_as_uint(zpart), zc = za;
    plswap(za, zc);
    float zq = __uint_as_float(za) + __uint_as_float(zc);
    if (l31 == l) zb[kh*64 + qh*32 + l31] = zq;   // lanes 0..31 only

    if (kh) {
        #pragma unroll
        for (int r = 0; r < 16; ++r) {
            int q = (r & 3) + 8*(r >> 2) + 4*hi;
            cb[(qh*32 + q)*64 + l31]      = acc0[r];
            cb[(qh*32 + q)*64 + 32 + l31] = acc1[r];
        }
    }
    __syncthreads();
    if (!kh) {
        #pragma unroll
        for (int r = 0; r < 16; ++r) {
            int q = (r & 3) + 8*(r >> 2) + 4*hi;
            float zt = zb[qh*32 + q] + zb[64 + qh*32 + q];
            float inv = 1.0f / zt;
            int s = s0 + qh*32 + q;
            size_t base = ((size_t)(b*SEQ + s))*1024 + h*64;
            float v0 = (acc0[r] + cb[(qh*32 + q)*64 + l31])      * inv;
            float v1 = (acc1[r] + cb[(qh*32 + q)*64 + 32 + l31]) * inv;
            ushort h0 = f2bf(v0);
            ushort h1 = f2bf(v1);
            hoh[base + l31]      = h0;
            hol[base + l31]      = f2bf(v0 - bf2f(h0));
            hoh[base + 32 + l31] = h1;
            hol[base + 32 + l31] = f2bf(v1 - bf2f(h1));
        }
    }
}

// ---------------------------------------------------------------------------
extern "C" void kernel_launch(void* const* d_in, const int* in_sizes, int n_in,
                              void* d_out, int out_size, void* d_ws, size_t ws_size,
                              hipStream_t stream)
{
    const float* x       = (const float*)d_in[0];
    const float* qkv_w   = (const float*)d_in[1];
    const float* out_w   = (const float*)d_in[2];
    const float* centers = (const float*)d_in[3];
    const float* lscales = (const float*)d_in[4];
    const float* amps    = (const float*)d_in[5];
    float* out  = (float*)d_out;                      // [B,S,D]
    float* traj = out + (size_t)NB*SEQ*DIM;           // [B,S,D]

    char* wsb = (char*)d_ws;                          // 40.03 MB total
    ushort* xh   = (ushort*)(wsb);                    // [0,8) MB  bf16 x hi
    ushort* xl   = (ushort*)(wsb + (8u<<20));         // [8,16) MB bf16 x lo
    ushort* wh   = (ushort*)(wsb + (16u<<20));        // [16,22) MB qkv_w hi (3072x1024)
    ushort* wlv  = (ushort*)(wsb + (22u<<20));        // [22,24) MB v-weight lo
    ushort* vbt  = (ushort*)(wsb + (24u<<20));        // [24,32) MB v^T bf16 [B,1024,S]
    float*  sbuf = (float*)(wsb + (40u<<20));         // 16 KB
    float*  invb = sbuf + 4096;                       // 16 KB
    // aliases (regions dead by the time they're written):
    ushort* qbuf = xl;                                // q bf16 head-major (xl dead after vgemm)
    ushort* kbuf = (ushort*)(wsb + (32u<<20));        // k bf16 head-major, [32,40) free
    ushort* qwbh = wlv;                               // splat-q out (after vgemm)
    ushort* kwbh = wh + 2048*1024;                    // wh [20,22) dead after vgemm
    ushort* owh  = wh;                                // wh [16,18) dead after qkgemm
    ushort* owl  = wh + 1048576;                      // wh [18,20)
    ushort* hoh  = xh;                                // after qkgemm (attn writes)
    ushort* hol  = xl;                                // after splat-q consumed qbuf

    // A: front conversions + traj stats
    front_kernel<<<8192, 256, 0, stream>>>(x, qkv_w, xh, xl, wh, wlv, sbuf, invb);
    // B: v^T = Wv @ x^T (split, bf16 transposed store) + traj[0,2048)
    gemmV_traj_kernel<<<2560, 256, 0, stream>>>(
        wh + 2048*1024, wlv, xh, xl, vbt, x, sbuf, invb, traj);
    // C: q,k projection (plain bf16, head-major out) + traj[2048,4096)
    gemmQK_traj_kernel<<<2560, 256, 0, stream>>>(
        xh, wh, qbuf, kbuf, x, sbuf, invb, traj);
    // D: splat weights (q and k) + out_w split cvt
    splat_cvt_kernel<<<1536, 256, 0, stream>>>(
        qbuf, kbuf, qwbh, kwbh, centers, lscales, amps, out_w, owh, owl);
    // E: attention
    attn_kernel<<<dim3(32, 32), 256, 0, stream>>>(qwbh, kwbh, vbt, hoh, hol);
    // F: out = ho @ out_w^T (split, fp32 out)
    gemmO_kernel<<<dim3(16, 32), 256, 0, stream>>>(hoh, hol, owh, owl, out);
}